// Round 6
// baseline (204.925 us; speedup 1.0000x reference)
//
#include <hip/hip_runtime.h>
#include <math.h>

// Problem constants: B=256, H=W=64, P=16, PH=PW=16, ZD=32, HD=1024, UD=3, IN=4096
#define SPLITK 8
#define PSUM_STRIDE 262144   // 256*1024

typedef __bf16 bf16x8 __attribute__((ext_vector_type(8)));
typedef float  f32x16 __attribute__((ext_vector_type(16)));

__device__ __forceinline__ unsigned short bf16rne(float x) {
    unsigned int u = __float_as_uint(x);
    unsigned int r = u + 0x7FFFu + ((u >> 16) & 1u);
    return (unsigned short)(r >> 16);
}
__device__ __forceinline__ float bf16tof(unsigned short h) {
    return __uint_as_float(((unsigned int)h) << 16);
}

// ---------------------------------------------------------------------------
// prepA: critical-path preprocessing only (W1 transpose-split + input convert).
// W2T / WT / parts moved into reduce_plus (off the gemm1 critical path).
// ---------------------------------------------------------------------------
__global__ __launch_bounds__(256) void prepA(
    const float* __restrict__ inputs, const float* __restrict__ W1,
    unsigned short* __restrict__ Ahi, unsigned short* __restrict__ Alo,
    unsigned short* __restrict__ W1Thi, unsigned short* __restrict__ W1Tlo)
{
    __shared__ float t[32][33];
    int bid = blockIdx.x;
    int tid = threadIdx.x;
    if (bid < 4096) {
        int n0 = (bid & 31) * 32, k0 = (bid >> 5) * 32;
        int c = tid & 31, r0 = tid >> 5;
#pragma unroll
        for (int i = 0; i < 4; i++)
            t[r0 + 8 * i][c] = W1[(size_t)(k0 + r0 + 8 * i) * 1024 + n0 + c];
        __syncthreads();
        int kk = tid & 31, n1 = tid >> 5;
#pragma unroll
        for (int i = 0; i < 4; i++) {
            float x = t[kk][n1 + 8 * i];
            unsigned short h = bf16rne(x);
            unsigned short l = bf16rne(x - bf16tof(h));
            size_t o = (size_t)(n0 + n1 + 8 * i) * 4096 + k0 + kk;
            W1Thi[o] = h;
            W1Tlo[o] = l;
        }
    } else {
        int id = ((bid - 4096) * 256 + tid) * 4;
        float4 x = *(const float4*)(inputs + id);
        ushort4 h, l;
        h.x = bf16rne(x.x); l.x = bf16rne(x.x - bf16tof(h.x));
        h.y = bf16rne(x.y); l.y = bf16rne(x.y - bf16tof(h.y));
        h.z = bf16rne(x.z); l.z = bf16rne(x.z - bf16tof(h.z));
        h.w = bf16rne(x.w); l.w = bf16rne(x.w - bf16tof(h.w));
        *(ushort4*)(Ahi + id) = h;
        *(ushort4*)(Alo + id) = l;
    }
}

// ---------------------------------------------------------------------------
// GEMM bf16x3: 64x64 tile, 4 waves, 32x32x16 MFMA, XOR-swizzled LDS. [r1-proven]
// ---------------------------------------------------------------------------
__global__ __launch_bounds__(256) void gemm_bf16x3(
    const unsigned short* __restrict__ Ahi, const unsigned short* __restrict__ Alo,
    const unsigned short* __restrict__ Bhi, const unsigned short* __restrict__ Blo,
    float* __restrict__ psum, int K, int kchunk)
{
    __shared__ unsigned short Ah[4096], Al[4096], Bh[4096], Bl[4096];
    int tid = threadIdx.x;
    int n0 = blockIdx.x * 64, m0 = blockIdx.y * 64;
    int kb = blockIdx.z * kchunk;
    int wid = tid >> 6, lane = tid & 63;
    int wm = wid & 1, wn = wid >> 1;
    int lr = lane & 31, hi = lane >> 5;

    int r0 = tid >> 3, ch0 = tid & 7;
    int r1 = (tid + 256) >> 3, ch1 = (tid + 256) & 7;
    int l0 = r0 * 64 + 8 * (ch0 ^ (r0 & 7));
    int l1 = r1 * 64 + 8 * (ch1 ^ (r1 & 7));
    size_t ga0 = (size_t)(m0 + r0) * K + kb + ch0 * 8;
    size_t ga1 = (size_t)(m0 + r1) * K + kb + ch1 * 8;
    size_t gb0 = (size_t)(n0 + r0) * K + kb + ch0 * 8;
    size_t gb1 = (size_t)(n0 + r1) * K + kb + ch1 * 8;

    f32x16 acc_hh = {}, acc_hl = {}, acc_lh = {};

    int nkt = kchunk >> 6;
    uint4 vah0, vah1, val0, val1, vbh0, vbh1, vbl0, vbl1;
    vah0 = *(const uint4*)(Ahi + ga0);
    vah1 = *(const uint4*)(Ahi + ga1);
    val0 = *(const uint4*)(Alo + ga0);
    val1 = *(const uint4*)(Alo + ga1);
    vbh0 = *(const uint4*)(Bhi + gb0);
    vbh1 = *(const uint4*)(Bhi + gb1);
    vbl0 = *(const uint4*)(Blo + gb0);
    vbl1 = *(const uint4*)(Blo + gb1);

    int basea = (wm * 32 + lr) * 64;
    int baseb = (wn * 32 + lr) * 64;
    int sw = lr & 7;

    for (int kt = 0; kt < nkt; kt++) {
        __syncthreads();
        *(uint4*)(Ah + l0) = vah0;
        *(uint4*)(Ah + l1) = vah1;
        *(uint4*)(Al + l0) = val0;
        *(uint4*)(Al + l1) = val1;
        *(uint4*)(Bh + l0) = vbh0;
        *(uint4*)(Bh + l1) = vbh1;
        *(uint4*)(Bl + l0) = vbl0;
        *(uint4*)(Bl + l1) = vbl1;
        __syncthreads();
        if (kt + 1 < nkt) {
            size_t o = (size_t)(kt + 1) * 64;
            vah0 = *(const uint4*)(Ahi + ga0 + o);
            vah1 = *(const uint4*)(Ahi + ga1 + o);
            val0 = *(const uint4*)(Alo + ga0 + o);
            val1 = *(const uint4*)(Alo + ga1 + o);
            vbh0 = *(const uint4*)(Bhi + gb0 + o);
            vbh1 = *(const uint4*)(Bhi + gb1 + o);
            vbl0 = *(const uint4*)(Blo + gb0 + o);
            vbl1 = *(const uint4*)(Blo + gb1 + o);
        }
#pragma unroll
        for (int s = 0; s < 4; s++) {
            int cidx = 8 * (((s << 1) + hi) ^ sw);
            bf16x8 afh = *(const bf16x8*)(Ah + basea + cidx);
            bf16x8 afl = *(const bf16x8*)(Al + basea + cidx);
            bf16x8 bfh = *(const bf16x8*)(Bh + baseb + cidx);
            bf16x8 bfl = *(const bf16x8*)(Bl + baseb + cidx);
            acc_hh = __builtin_amdgcn_mfma_f32_32x32x16_bf16(afh, bfh, acc_hh, 0, 0, 0);
            acc_hl = __builtin_amdgcn_mfma_f32_32x32x16_bf16(afh, bfl, acc_hl, 0, 0, 0);
            acc_lh = __builtin_amdgcn_mfma_f32_32x32x16_bf16(afl, bfh, acc_lh, 0, 0, 0);
        }
    }

    float* op = psum + (size_t)blockIdx.z * PSUM_STRIDE;
    int colg = n0 + wn * 32 + lr;
#pragma unroll
    for (int r = 0; r < 16; r++) {
        int rowl = (r & 3) + 8 * (r >> 2) + 4 * hi;
        op[(size_t)(m0 + wm * 32 + rowl) * 1024 + colg] = acc_hh[r] + acc_hl[r] + acc_lh[r];
    }
}

// ---------------------------------------------------------------------------
// reduce_plus: layer-1 reduce+bias+relu+split (bid<256), plus the
// non-critical prep moved here: W2 transpose (256..1279), head-weight
// re-layout (1280..1687), parts colsum (1688..1703).
// ---------------------------------------------------------------------------
__global__ __launch_bounds__(256) void reduce_plus(
    const float* __restrict__ psum, const float* __restrict__ bias,
    unsigned short* __restrict__ hi, unsigned short* __restrict__ lo,
    const float* __restrict__ W2,
    unsigned short* __restrict__ W2Thi, unsigned short* __restrict__ W2Tlo,
    const float* __restrict__ Wum, const float* __restrict__ Wuv,
    const float* __restrict__ Wgm, const float* __restrict__ Wgv,
    const float* __restrict__ Wz,
    float* __restrict__ WT, float* __restrict__ partsb)
{
    __shared__ float t[32][33];
    int bid = blockIdx.x;
    int tid = threadIdx.x;
    if (bid < 256) {
        int i = (bid * 256 + tid) * 4;
        float4 v = *(const float4*)(psum + i);
#pragma unroll
        for (int s = 1; s < SPLITK; s++) {
            float4 tt = *(const float4*)(psum + (size_t)s * PSUM_STRIDE + i);
            v.x += tt.x; v.y += tt.y; v.z += tt.z; v.w += tt.w;
        }
        float4 bb = *(const float4*)(bias + (i & 1023));
        v.x = fmaxf(v.x + bb.x, 0.f);
        v.y = fmaxf(v.y + bb.y, 0.f);
        v.z = fmaxf(v.z + bb.z, 0.f);
        v.w = fmaxf(v.w + bb.w, 0.f);
        ushort4 h, l;
        h.x = bf16rne(v.x); l.x = bf16rne(v.x - bf16tof(h.x));
        h.y = bf16rne(v.y); l.y = bf16rne(v.y - bf16tof(h.y));
        h.z = bf16rne(v.z); l.z = bf16rne(v.z - bf16tof(h.z));
        h.w = bf16rne(v.w); l.w = bf16rne(v.w - bf16tof(h.w));
        *(ushort4*)(hi + i) = h;
        *(ushort4*)(lo + i) = l;
    } else if (bid < 1280) {
        int b2 = bid - 256;
        int n0 = (b2 & 31) * 32, k0 = (b2 >> 5) * 32;
        int c = tid & 31, r0 = tid >> 5;
#pragma unroll
        for (int i = 0; i < 4; i++)
            t[r0 + 8 * i][c] = W2[(size_t)(k0 + r0 + 8 * i) * 1024 + n0 + c];
        __syncthreads();
        int kk = tid & 31, n1 = tid >> 5;
#pragma unroll
        for (int i = 0; i < 4; i++) {
            float x = t[kk][n1 + 8 * i];
            unsigned short h = bf16rne(x);
            unsigned short l = bf16rne(x - bf16tof(h));
            size_t o = (size_t)(n0 + n1 + 8 * i) * 1024 + k0 + kk;
            W2Thi[o] = h;
            W2Tlo[o] = l;
        }
    } else if (bid < 1688) {
        int id = (bid - 1280) * 256 + tid;
        int o = id >> 10;
        int k = id & 1023;
        float v;
        if (o < 48)       v = Wum[k * 48 + o];
        else if (o < 96)  v = Wuv[k * 48 + (o - 48)];
        else if (o < 99)  v = Wgm[k * 3 + (o - 96)];
        else              v = Wgv[k * 3 + (o - 99)];
        WT[id] = v;
    } else {
        int idx = (bid - 1688) * 256 + tid;
        float s = 0.f;
#pragma unroll
        for (int z = 0; z < 32; z++) s += Wz[z * 4096 + idx];
        partsb[idx] = 1.f / (1.f + expf(-s));
    }
}

// ---------------------------------------------------------------------------
// composite_half: 512 blocks x 512 threads -- TWO independent blocks per
// batch image (rows 0-31 / 32-63), giving 2 barrier-domains per CU so one
// block's stalls hide under the other's compute (r5 showed barriers/ILP
// within ONE domain are not the limiter; TLP across domains is untried).
// Per-pixel math is bit-identical to the r3-proven code. Writes x to ws;
// the global gu-transform moves to final_transform.
// ---------------------------------------------------------------------------
__global__ __launch_bounds__(512) void composite_half(
    const float* __restrict__ psum, const float* __restrict__ b2,
    const float* __restrict__ WT,
    const float* __restrict__ bum, const float* __restrict__ buv,
    const float* __restrict__ bgm, const float* __restrict__ bgv,
    const float* __restrict__ eps_u, const float* __restrict__ eps_g,
    const float* __restrict__ M, const float* __restrict__ parts,
    float* __restrict__ xl_out, float* __restrict__ gu_out)
{
    __shared__ float patch[4096];
    __shared__ float plane[2][4096];
    __shared__ float h2[1024];
    __shared__ float u_raw[51];
    __shared__ float pc[16], psn[16], ptx[16], pty[16], pwx[16], pwy[16];
    __shared__ int pix[16], piy[16];
    int bx = blockIdx.x;
    int b = bx & 255, hf = bx >> 8;
    int tid = threadIdx.x;

    // ---- heads prologue: layer-2 reduce for row b (2 elems/thread) ----
#pragma unroll
    for (int e = 0; e < 2; e++) {
        int idx = tid + e * 512;
        float v = psum[(size_t)b * 1024 + idx];
#pragma unroll
        for (int s = 1; s < SPLITK; s++)
            v += psum[(size_t)s * PSUM_STRIDE + (size_t)b * 1024 + idx];
        h2[idx] = fmaxf(v + b2[idx], 0.f);
    }
    for (int i = tid; i < 4096; i += 512) patch[i] = parts[i];
    __syncthreads();

    // ---- head matvecs (identical per-o math; o strides by 8 waves) ----
    {
        int w = tid >> 6, l = tid & 63;
        const float4* h4 = (const float4*)h2;
        float4 hr0 = h4[l], hr1 = h4[64 + l], hr2 = h4[128 + l], hr3 = h4[192 + l];
        for (int o = w; o < 51; o += 8) {
            int rm = (o < 48) ? o : (48 + o);
            int rv = (o < 48) ? (o + 48) : (51 + o);
            const float* wpm = WT + rm * 1024 + l * 4;
            const float* wpv = WT + rv * 1024 + l * 4;
            float4 wm0 = *(const float4*)(wpm);
            float4 wm1 = *(const float4*)(wpm + 256);
            float4 wm2 = *(const float4*)(wpm + 512);
            float4 wm3 = *(const float4*)(wpm + 768);
            float4 wv0 = *(const float4*)(wpv);
            float4 wv1 = *(const float4*)(wpv + 256);
            float4 wv2 = *(const float4*)(wpv + 512);
            float4 wv3 = *(const float4*)(wpv + 768);
            float am = 0.f, av = 0.f;
            am = fmaf(hr0.x, wm0.x, am); am = fmaf(hr0.y, wm0.y, am);
            am = fmaf(hr0.z, wm0.z, am); am = fmaf(hr0.w, wm0.w, am);
            av = fmaf(hr0.x, wv0.x, av); av = fmaf(hr0.y, wv0.y, av);
            av = fmaf(hr0.z, wv0.z, av); av = fmaf(hr0.w, wv0.w, av);
            am = fmaf(hr1.x, wm1.x, am); am = fmaf(hr1.y, wm1.y, am);
            am = fmaf(hr1.z, wm1.z, am); am = fmaf(hr1.w, wm1.w, am);
            av = fmaf(hr1.x, wv1.x, av); av = fmaf(hr1.y, wv1.y, av);
            av = fmaf(hr1.z, wv1.z, av); av = fmaf(hr1.w, wv1.w, av);
            am = fmaf(hr2.x, wm2.x, am); am = fmaf(hr2.y, wm2.y, am);
            am = fmaf(hr2.z, wm2.z, am); am = fmaf(hr2.w, wm2.w, am);
            av = fmaf(hr2.x, wv2.x, av); av = fmaf(hr2.y, wv2.y, av);
            av = fmaf(hr2.z, wv2.z, av); av = fmaf(hr2.w, wv2.w, av);
            am = fmaf(hr3.x, wm3.x, am); am = fmaf(hr3.y, wm3.y, am);
            am = fmaf(hr3.z, wm3.z, am); am = fmaf(hr3.w, wm3.w, am);
            av = fmaf(hr3.x, wv3.x, av); av = fmaf(hr3.y, wv3.y, av);
            av = fmaf(hr3.z, wv3.z, av); av = fmaf(hr3.w, wv3.w, av);
#pragma unroll
            for (int s = 32; s; s >>= 1) {
                am += __shfl_xor(am, s, 64);
                av += __shfl_xor(av, s, 64);
            }
            if (l == 0) {
                if (o < 48) {
                    float umu = tanhf(am + bum[o]);
                    float uvar = expf(fmaxf(av + buv[o], -6.f));   // threshold(-6,-6)
                    u_raw[o] = umu + uvar * eps_u[b * 48 + o];
                } else {
                    int n = o - 48;
                    float gmu = tanhf(am + bgm[n]);
                    float gpre = av + bgv[n];
                    float gvar = expf(gpre > -6.f ? gpre : 6.f);   // threshold(-6,6)
                    float gv = gmu + gvar * eps_g[b * 3 + n];
                    u_raw[o] = gv;
                    gu_out[b * 3 + n] = gv;   // both halves store identical bits
                }
            }
        }
    }
    __syncthreads();

    // ---- compositing setup + plane 0 staging ----
    if (tid < 16) {
        float ang = u_raw[tid * 3 + 0];
        float tx = u_raw[tid * 3 + 1], ty = u_raw[tid * 3 + 2];
        pc[tid] = cosf(ang);
        psn[tid] = sinf(ang);
        ptx[tid] = tx;
        pty[tid] = ty;
        float ax = fminf(fmaxf(32.f * tx, -16384.f), 16384.f);
        float fax = floorf(ax);
        pwx[tid] = ax - fax;
        pix[tid] = (int)fax;
        float ay = fminf(fmaxf(32.f * ty, -16384.f), 16384.f);
        float fay = floorf(ay);
        pwy[tid] = ay - fay;
        piy[tid] = (int)fay;
    }
    const float* Mb = M + ((size_t)(b * 16) << 12);
    ((float4*)plane[0])[tid] = ((const float4*)Mb)[tid];
    ((float4*)plane[0])[tid + 512] = ((const float4*)Mb)[tid + 512];
    float4 pf0 = ((const float4*)(Mb + 4096))[tid];
    float4 pf1 = ((const float4*)(Mb + 4096))[tid + 512];
    __syncthreads();

    int j = tid & 63;
    int i0 = hf * 32 + (tid >> 6) * 4;
    float xnv = (float)(2 * j + 1) * (1.f / 64.f) - 1.f;
    float ynv0 = (float)(2 * i0 + 1) * (1.f / 64.f) - 1.f;

    float num[4] = {}, den[4] = {};
    float* pl_cur = plane[0];
    float* pl_nxt = plane[1];

    for (int p = 0; p < 16; p++) {
        if (p + 1 < 16) {
            ((float4*)pl_nxt)[tid] = pf0;
            ((float4*)pl_nxt)[tid + 512] = pf1;
        }
        if (p + 2 < 16) {
            pf0 = ((const float4*)(Mb + ((size_t)(p + 2) << 12)))[tid];
            pf1 = ((const float4*)(Mb + ((size_t)(p + 2) << 12)))[tid + 512];
        }

        int dx = 8 * (p & 3) - 12;
        int dy = 8 * (p >> 2) - 12;
        float c = pc[p], s = psn[p], tx = ptx[p], ty = pty[p];
        float wx = pwx[p], wy = pwy[p];
        int ix = pix[p], iy = piy[p];
        int iY = iy + dy;

        int x0 = j + ix;
        int X = x0 + dx;
        bool vc0 = ((unsigned)x0 < 64u) && ((unsigned)X < 64u);
        bool vc1 = ((unsigned)(x0 + 1) < 64u) && ((unsigned)(X + 1) < 64u);
        float w0 = vc0 ? (1.f - wx) : 0.f;
        float w1 = vc1 ? wx : 0.f;
        int Xc0 = min(max(X, 0), 63);
        int Xc1 = min(max(X + 1, 0), 63);

        const float* pl = pl_cur;
        float R[5];
#pragma unroll
        for (int r = 0; r < 5; r++) {
            int i = i0 + r;
            int ri = i + iY;
            bool vr = ((unsigned)(i + iy) < 64u) && ((unsigned)ri < 64u);
            int ric = min(max(ri, 0), 63);
            const float* row = pl + (ric << 6);
            float val = fmaf(w0, row[Xc0], w1 * row[Xc1]);
            R[r] = vr ? val : 0.f;
        }

        float gx0 = fmaf(-s, ynv0, fmaf(c, xnv, tx));
        float gy0 = fmaf(c, ynv0, fmaf(s, xnv, ty));
        float xs = fmaf(gx0, 32.f, 31.5f);
        float ysv = fmaf(gy0, 32.f, 31.5f);
        int ox = 24 - dx, oy = 24 - dy;
        float oxf = (float)ox, oyf = (float)oy;
        const float* pp = patch + (p << 8);
#pragma unroll
        for (int r = 0; r < 4; r++) {
            float km = fmaf(wy, R[r + 1] - R[r], R[r]);
            den[r] += km;

            if (xs >= oxf - 1.f && xs < oxf + 16.f &&
                ysv >= oyf - 1.f && ysv < oyf + 16.f) {
                float xf = floorf(xs), yf = floorf(ysv);
                float wxx = xs - xf, wyy = ysv - yf;
                int a0 = (int)yf - oy;
                int b0c = (int)xf - ox;
                float v00 = 0.f, v10 = 0.f, v01 = 0.f, v11 = 0.f;
                if ((unsigned)a0 < 16u) {
                    const float* pr = pp + a0 * 16;
                    if ((unsigned)b0c < 16u) v00 = pr[b0c];
                    if ((unsigned)(b0c + 1) < 16u) v10 = pr[b0c + 1];
                }
                if ((unsigned)(a0 + 1) < 16u) {
                    const float* pr = pp + (a0 + 1) * 16;
                    if ((unsigned)b0c < 16u) v01 = pr[b0c];
                    if ((unsigned)(b0c + 1) < 16u) v11 = pr[b0c + 1];
                }
                float top = fmaf(wxx, v10 - v00, v00);
                float bot = fmaf(wxx, v11 - v01, v01);
                float xp = fmaf(wyy, bot - top, top);
                num[r] = fmaf(xp, km, num[r]);
            }
            xs -= s;   // d(xs)/d(row) = -s
            ysv += c;  // d(ys)/d(row) = +c
        }
        __syncthreads();
        float* tmp = pl_cur; pl_cur = pl_nxt; pl_nxt = tmp;
    }

    float* xo = xl_out + ((size_t)b << 12);
#pragma unroll
    for (int r = 0; r < 4; r++) {
        float d = (den[r] == 0.f) ? 1.f : den[r];
        xo[(i0 + r) * 64 + j] = num[r] / d;
    }
}

// ---------------------------------------------------------------------------
// final_transform: global gu rotation+translation resample of x -> out.
// 256 blocks x 1024 threads; stages x (16 KB) to LDS, code identical to the
// proven composite tail.
// ---------------------------------------------------------------------------
__global__ __launch_bounds__(1024) void final_transform(
    const float* __restrict__ xl_in, const float* __restrict__ gu,
    float* __restrict__ out)
{
    __shared__ float xl[4096];
    int b = blockIdx.x;
    int tid = threadIdx.x;
    ((float4*)xl)[tid] = ((const float4*)(xl_in + ((size_t)b << 12)))[tid];
    __syncthreads();

    int j = tid & 63;
    int i0 = (tid >> 6) * 4;
    float xnv = (float)(2 * j + 1) * (1.f / 64.f) - 1.f;

    float ang = gu[b * 3 + 0], gtx = gu[b * 3 + 1], gty = gu[b * 3 + 2];
    float cg = cosf(ang), sg = sinf(ang);
    float* ob = out + ((size_t)b << 12);
#pragma unroll
    for (int r = 0; r < 4; r++) {
        int i = i0 + r;
        float ynv = (float)(2 * i + 1) * (1.f / 64.f) - 1.f;
        float gx = cg * xnv - sg * ynv + gtx;
        float gy = sg * xnv + cg * ynv + gty;
        gx = fminf(fmaxf(gx, -8.f), 8.f);
        gy = fminf(fmaxf(gy, -8.f), 8.f);
        float xs = fmaf(gx, 32.f, 31.5f);
        float ysv = fmaf(gy, 32.f, 31.5f);
        float xf = floorf(xs), yf = floorf(ysv);
        float wx = xs - xf, wy = ysv - yf;
        int x0 = (int)xf, y0 = (int)yf;
        float v00 = 0.f, v10 = 0.f, v01 = 0.f, v11 = 0.f;
        bool vx0 = (unsigned)x0 < 64u, vx1 = (unsigned)(x0 + 1) < 64u;
        if ((unsigned)y0 < 64u) {
            const float* row = xl + y0 * 64;
            if (vx0) v00 = row[x0];
            if (vx1) v10 = row[x0 + 1];
        }
        if ((unsigned)(y0 + 1) < 64u) {
            const float* row = xl + (y0 + 1) * 64;
            if (vx0) v01 = row[x0];
            if (vx1) v11 = row[x0 + 1];
        }
        float top = fmaf(wx, v10 - v00, v00);
        float bot = fmaf(wx, v11 - v01, v01);
        ob[i * 64 + j] = fmaf(wy, bot - top, top);
    }
}

// ---------------------------------------------------------------------------
extern "C" void kernel_launch(void* const* d_in, const int* in_sizes, int n_in,
                              void* d_out, int out_size, void* d_ws, size_t ws_size,
                              hipStream_t stream)
{
    (void)in_sizes; (void)n_in; (void)out_size; (void)ws_size;
    const float* inputs = (const float*)d_in[0];
    const float* W1  = (const float*)d_in[1];
    const float* b1  = (const float*)d_in[2];
    const float* W2  = (const float*)d_in[3];
    const float* b2  = (const float*)d_in[4];
    const float* Wum = (const float*)d_in[5];
    const float* bum = (const float*)d_in[6];
    const float* Wuv = (const float*)d_in[7];
    const float* buv = (const float*)d_in[8];
    const float* Wgm = (const float*)d_in[9];
    const float* bgm = (const float*)d_in[10];
    const float* Wgv = (const float*)d_in[11];
    const float* bgv = (const float*)d_in[12];
    const float* Wz  = (const float*)d_in[13];
    const float* Mm  = (const float*)d_in[14];
    const float* eps_u = (const float*)d_in[15];
    const float* eps_g = (const float*)d_in[16];

    float* ws = (float*)d_ws;
    float* psum      = ws;                     // 8 x 262144 floats
    float* parts_buf = psum + 8 * PSUM_STRIDE; // 4,096
    float* WTh_buf   = parts_buf + 4096;       // 104,448
    unsigned short* us = (unsigned short*)(WTh_buf + 104448);
    unsigned short* Ahi   = us;                 // 1,048,576
    unsigned short* Alo   = Ahi + 1048576;
    unsigned short* W1Thi = Alo + 1048576;      // 4,194,304
    unsigned short* W1Tlo = W1Thi + 4194304;
    unsigned short* W2Thi = W1Tlo + 4194304;    // 1,048,576
    unsigned short* W2Tlo = W2Thi + 1048576;
    unsigned short* H1hi  = W2Tlo + 1048576;    // 262,144
    unsigned short* H1lo  = H1hi + 262144;
    float* xl_buf = (float*)(H1lo + 262144);    // 1,048,576 floats (4 MB)
    float* gu_buf = xl_buf + 1048576;           // 768 floats

    // Critical-path preprocessing: W1 transpose-split + input convert
    prepA<<<5120, 256, 0, stream>>>(inputs, W1, Ahi, Alo, W1Thi, W1Tlo);

    // MLP layer 1: [256,4096] @ [4096,1024], bf16x3 MFMA split-K=8
    gemm_bf16x3<<<dim3(16, 4, SPLITK), 256, 0, stream>>>(Ahi, Alo, W1Thi, W1Tlo,
                                                         psum, 4096, 4096 / SPLITK);
    // Layer-1 reduce + the non-critical prep (W2T, WT, parts)
    reduce_plus<<<1704, 256, 0, stream>>>(psum, b1, H1hi, H1lo,
                                          W2, W2Thi, W2Tlo,
                                          Wum, Wuv, Wgm, Wgv, Wz,
                                          WTh_buf, parts_buf);
    // MLP layer 2: [256,1024] @ [1024,1024], split-K=8
    gemm_bf16x3<<<dim3(16, 4, SPLITK), 256, 0, stream>>>(H1hi, H1lo, W2Thi, W2Tlo,
                                                         psum, 1024, 1024 / SPLITK);
    // Heads + compositing (two half-image blocks per batch) -> x in ws
    composite_half<<<512, 512, 0, stream>>>(psum, b2, WTh_buf, bum, buv,
                                            bgm, bgv, eps_u, eps_g,
                                            Mm, parts_buf, xl_buf, gu_buf);
    // Global gu transform -> out [256,1,64,64]
    final_transform<<<256, 1024, 0, stream>>>(xl_buf, gu_buf, (float*)d_out);
}

// Round 7
// 200.591 us; speedup vs baseline: 1.0216x; 1.0216x over previous
//
#include <hip/hip_runtime.h>
#include <math.h>

// Problem constants: B=256, H=W=64, P=16, PH=PW=16, ZD=32, HD=1024, UD=3, IN=4096
#define SPLITK 8
#define PSUM_STRIDE 262144   // 256*1024

typedef __bf16 bf16x8 __attribute__((ext_vector_type(8)));
typedef float  f32x16 __attribute__((ext_vector_type(16)));

__device__ __forceinline__ unsigned short bf16rne(float x) {
    unsigned int u = __float_as_uint(x);
    unsigned int r = u + 0x7FFFu + ((u >> 16) & 1u);
    return (unsigned short)(r >> 16);
}
__device__ __forceinline__ float bf16tof(unsigned short h) {
    return __uint_as_float(((unsigned int)h) << 16);
}

// ---------------------------------------------------------------------------
// prepA: critical-path preprocessing only (W1 transpose-split + input convert).
// ---------------------------------------------------------------------------
__global__ __launch_bounds__(256) void prepA(
    const float* __restrict__ inputs, const float* __restrict__ W1,
    unsigned short* __restrict__ Ahi, unsigned short* __restrict__ Alo,
    unsigned short* __restrict__ W1Thi, unsigned short* __restrict__ W1Tlo)
{
    __shared__ float t[32][33];
    int bid = blockIdx.x;
    int tid = threadIdx.x;
    if (bid < 4096) {
        int n0 = (bid & 31) * 32, k0 = (bid >> 5) * 32;
        int c = tid & 31, r0 = tid >> 5;
#pragma unroll
        for (int i = 0; i < 4; i++)
            t[r0 + 8 * i][c] = W1[(size_t)(k0 + r0 + 8 * i) * 1024 + n0 + c];
        __syncthreads();
        int kk = tid & 31, n1 = tid >> 5;
#pragma unroll
        for (int i = 0; i < 4; i++) {
            float x = t[kk][n1 + 8 * i];
            unsigned short h = bf16rne(x);
            unsigned short l = bf16rne(x - bf16tof(h));
            size_t o = (size_t)(n0 + n1 + 8 * i) * 4096 + k0 + kk;
            W1Thi[o] = h;
            W1Tlo[o] = l;
        }
    } else {
        int id = ((bid - 4096) * 256 + tid) * 4;
        float4 x = *(const float4*)(inputs + id);
        ushort4 h, l;
        h.x = bf16rne(x.x); l.x = bf16rne(x.x - bf16tof(h.x));
        h.y = bf16rne(x.y); l.y = bf16rne(x.y - bf16tof(h.y));
        h.z = bf16rne(x.z); l.z = bf16rne(x.z - bf16tof(h.z));
        h.w = bf16rne(x.w); l.w = bf16rne(x.w - bf16tof(h.w));
        *(ushort4*)(Ahi + id) = h;
        *(ushort4*)(Alo + id) = l;
    }
}

// ---------------------------------------------------------------------------
// GEMM bf16x3: 64x64 tile, 4 waves, 32x32x16 MFMA, XOR-swizzled LDS. [r1-proven]
// ---------------------------------------------------------------------------
__global__ __launch_bounds__(256) void gemm_bf16x3(
    const unsigned short* __restrict__ Ahi, const unsigned short* __restrict__ Alo,
    const unsigned short* __restrict__ Bhi, const unsigned short* __restrict__ Blo,
    float* __restrict__ psum, int K, int kchunk)
{
    __shared__ unsigned short Ah[4096], Al[4096], Bh[4096], Bl[4096];
    int tid = threadIdx.x;
    int n0 = blockIdx.x * 64, m0 = blockIdx.y * 64;
    int kb = blockIdx.z * kchunk;
    int wid = tid >> 6, lane = tid & 63;
    int wm = wid & 1, wn = wid >> 1;
    int lr = lane & 31, hi = lane >> 5;

    int r0 = tid >> 3, ch0 = tid & 7;
    int r1 = (tid + 256) >> 3, ch1 = (tid + 256) & 7;
    int l0 = r0 * 64 + 8 * (ch0 ^ (r0 & 7));
    int l1 = r1 * 64 + 8 * (ch1 ^ (r1 & 7));
    size_t ga0 = (size_t)(m0 + r0) * K + kb + ch0 * 8;
    size_t ga1 = (size_t)(m0 + r1) * K + kb + ch1 * 8;
    size_t gb0 = (size_t)(n0 + r0) * K + kb + ch0 * 8;
    size_t gb1 = (size_t)(n0 + r1) * K + kb + ch1 * 8;

    f32x16 acc_hh = {}, acc_hl = {}, acc_lh = {};

    int nkt = kchunk >> 6;
    uint4 vah0, vah1, val0, val1, vbh0, vbh1, vbl0, vbl1;
    vah0 = *(const uint4*)(Ahi + ga0);
    vah1 = *(const uint4*)(Ahi + ga1);
    val0 = *(const uint4*)(Alo + ga0);
    val1 = *(const uint4*)(Alo + ga1);
    vbh0 = *(const uint4*)(Bhi + gb0);
    vbh1 = *(const uint4*)(Bhi + gb1);
    vbl0 = *(const uint4*)(Blo + gb0);
    vbl1 = *(const uint4*)(Blo + gb1);

    int basea = (wm * 32 + lr) * 64;
    int baseb = (wn * 32 + lr) * 64;
    int sw = lr & 7;

    for (int kt = 0; kt < nkt; kt++) {
        __syncthreads();
        *(uint4*)(Ah + l0) = vah0;
        *(uint4*)(Ah + l1) = vah1;
        *(uint4*)(Al + l0) = val0;
        *(uint4*)(Al + l1) = val1;
        *(uint4*)(Bh + l0) = vbh0;
        *(uint4*)(Bh + l1) = vbh1;
        *(uint4*)(Bl + l0) = vbl0;
        *(uint4*)(Bl + l1) = vbl1;
        __syncthreads();
        if (kt + 1 < nkt) {
            size_t o = (size_t)(kt + 1) * 64;
            vah0 = *(const uint4*)(Ahi + ga0 + o);
            vah1 = *(const uint4*)(Ahi + ga1 + o);
            val0 = *(const uint4*)(Alo + ga0 + o);
            val1 = *(const uint4*)(Alo + ga1 + o);
            vbh0 = *(const uint4*)(Bhi + gb0 + o);
            vbh1 = *(const uint4*)(Bhi + gb1 + o);
            vbl0 = *(const uint4*)(Blo + gb0 + o);
            vbl1 = *(const uint4*)(Blo + gb1 + o);
        }
#pragma unroll
        for (int s = 0; s < 4; s++) {
            int cidx = 8 * (((s << 1) + hi) ^ sw);
            bf16x8 afh = *(const bf16x8*)(Ah + basea + cidx);
            bf16x8 afl = *(const bf16x8*)(Al + basea + cidx);
            bf16x8 bfh = *(const bf16x8*)(Bh + baseb + cidx);
            bf16x8 bfl = *(const bf16x8*)(Bl + baseb + cidx);
            acc_hh = __builtin_amdgcn_mfma_f32_32x32x16_bf16(afh, bfh, acc_hh, 0, 0, 0);
            acc_hl = __builtin_amdgcn_mfma_f32_32x32x16_bf16(afh, bfl, acc_hl, 0, 0, 0);
            acc_lh = __builtin_amdgcn_mfma_f32_32x32x16_bf16(afl, bfh, acc_lh, 0, 0, 0);
        }
    }

    float* op = psum + (size_t)blockIdx.z * PSUM_STRIDE;
    int colg = n0 + wn * 32 + lr;
#pragma unroll
    for (int r = 0; r < 16; r++) {
        int rowl = (r & 3) + 8 * (r >> 2) + 4 * hi;
        op[(size_t)(m0 + wm * 32 + rowl) * 1024 + colg] = acc_hh[r] + acc_hl[r] + acc_lh[r];
    }
}

// ---------------------------------------------------------------------------
// reduce_plus: layer-1 reduce+bias+relu+split (bid<256), plus the
// non-critical prep: W2 transpose (256..1279), head weights (1280..1687),
// parts colsum (1688..1703).  [r6-proven]
// ---------------------------------------------------------------------------
__global__ __launch_bounds__(256) void reduce_plus(
    const float* __restrict__ psum, const float* __restrict__ bias,
    unsigned short* __restrict__ hi, unsigned short* __restrict__ lo,
    const float* __restrict__ W2,
    unsigned short* __restrict__ W2Thi, unsigned short* __restrict__ W2Tlo,
    const float* __restrict__ Wum, const float* __restrict__ Wuv,
    const float* __restrict__ Wgm, const float* __restrict__ Wgv,
    const float* __restrict__ Wz,
    float* __restrict__ WT, float* __restrict__ partsb)
{
    __shared__ float t[32][33];
    int bid = blockIdx.x;
    int tid = threadIdx.x;
    if (bid < 256) {
        int i = (bid * 256 + tid) * 4;
        float4 v = *(const float4*)(psum + i);
#pragma unroll
        for (int s = 1; s < SPLITK; s++) {
            float4 tt = *(const float4*)(psum + (size_t)s * PSUM_STRIDE + i);
            v.x += tt.x; v.y += tt.y; v.z += tt.z; v.w += tt.w;
        }
        float4 bb = *(const float4*)(bias + (i & 1023));
        v.x = fmaxf(v.x + bb.x, 0.f);
        v.y = fmaxf(v.y + bb.y, 0.f);
        v.z = fmaxf(v.z + bb.z, 0.f);
        v.w = fmaxf(v.w + bb.w, 0.f);
        ushort4 h, l;
        h.x = bf16rne(v.x); l.x = bf16rne(v.x - bf16tof(h.x));
        h.y = bf16rne(v.y); l.y = bf16rne(v.y - bf16tof(h.y));
        h.z = bf16rne(v.z); l.z = bf16rne(v.z - bf16tof(h.z));
        h.w = bf16rne(v.w); l.w = bf16rne(v.w - bf16tof(h.w));
        *(ushort4*)(hi + i) = h;
        *(ushort4*)(lo + i) = l;
    } else if (bid < 1280) {
        int b2 = bid - 256;
        int n0 = (b2 & 31) * 32, k0 = (b2 >> 5) * 32;
        int c = tid & 31, r0 = tid >> 5;
#pragma unroll
        for (int i = 0; i < 4; i++)
            t[r0 + 8 * i][c] = W2[(size_t)(k0 + r0 + 8 * i) * 1024 + n0 + c];
        __syncthreads();
        int kk = tid & 31, n1 = tid >> 5;
#pragma unroll
        for (int i = 0; i < 4; i++) {
            float x = t[kk][n1 + 8 * i];
            unsigned short h = bf16rne(x);
            unsigned short l = bf16rne(x - bf16tof(h));
            size_t o = (size_t)(n0 + n1 + 8 * i) * 1024 + k0 + kk;
            W2Thi[o] = h;
            W2Tlo[o] = l;
        }
    } else if (bid < 1688) {
        int id = (bid - 1280) * 256 + tid;
        int o = id >> 10;
        int k = id & 1023;
        float v;
        if (o < 48)       v = Wum[k * 48 + o];
        else if (o < 96)  v = Wuv[k * 48 + (o - 48)];
        else if (o < 99)  v = Wgm[k * 3 + (o - 96)];
        else              v = Wgv[k * 3 + (o - 99)];
        WT[id] = v;
    } else {
        int idx = (bid - 1688) * 256 + tid;
        float s = 0.f;
#pragma unroll
        for (int z = 0; z < 32; z++) s += Wz[z * 4096 + idx];
        partsb[idx] = 1.f / (1.f + expf(-s));
    }
}

// ---------------------------------------------------------------------------
// composite_direct: M read DIRECTLY from global (L2-resident; each block's
// 64 KB x 32 blocks/XCD = 2 MB < 4 MB L2) -- no plane LDS, no staging
// writes, and ZERO barriers in the p-loop (waves free-run across parts).
// r3/r5/r6 showed barriers/ILP/TLP around LDS staging were all null; the
// staging itself was the overhead (guide common-mistake #7).
// Final gu transform fused back (r6 split cost ~11 us).
// 256 blocks x 1024 threads; LDS ~37 KB, VGPR ~40 -> 2 blocks/CU possible.
// Per-pixel math bit-identical to the r3-proven code.
// ---------------------------------------------------------------------------
__global__ __launch_bounds__(1024) void composite_direct(
    const float* __restrict__ psum, const float* __restrict__ b2,
    const float* __restrict__ WT,
    const float* __restrict__ bum, const float* __restrict__ buv,
    const float* __restrict__ bgm, const float* __restrict__ bgv,
    const float* __restrict__ eps_u, const float* __restrict__ eps_g,
    const float* __restrict__ M, const float* __restrict__ parts,
    float* __restrict__ out)
{
    __shared__ float patch[4096];   // 16 KB
    __shared__ float xl[4096];      // 16 KB
    __shared__ float h2[1024];      // 4 KB
    __shared__ float u_raw[51];
    __shared__ float pc[16], psn[16], ptx[16], pty[16], pwx[16], pwy[16];
    __shared__ int pix[16], piy[16];
    int b = blockIdx.x;
    int tid = threadIdx.x;

    const float* Mb = M + ((size_t)(b * 16) << 12);

    // ---- heads prologue: layer-2 reduce for row b ----
    {
        float v = psum[(size_t)b * 1024 + tid];
#pragma unroll
        for (int s = 1; s < SPLITK; s++)
            v += psum[(size_t)s * PSUM_STRIDE + (size_t)b * 1024 + tid];
        h2[tid] = fmaxf(v + b2[tid], 0.f);
    }
    for (int i = tid; i < 4096; i += 1024) patch[i] = parts[i];
    __syncthreads();

    // ---- head matvecs (same summation order as heads_v3) ----
    {
        int w = tid >> 6, l = tid & 63;
        const float4* h4 = (const float4*)h2;
        float4 hr0 = h4[l], hr1 = h4[64 + l], hr2 = h4[128 + l], hr3 = h4[192 + l];
        for (int o = w; o < 51; o += 16) {
            int rm = (o < 48) ? o : (48 + o);
            int rv = (o < 48) ? (o + 48) : (51 + o);
            const float* wpm = WT + rm * 1024 + l * 4;
            const float* wpv = WT + rv * 1024 + l * 4;
            float4 wm0 = *(const float4*)(wpm);
            float4 wm1 = *(const float4*)(wpm + 256);
            float4 wm2 = *(const float4*)(wpm + 512);
            float4 wm3 = *(const float4*)(wpm + 768);
            float4 wv0 = *(const float4*)(wpv);
            float4 wv1 = *(const float4*)(wpv + 256);
            float4 wv2 = *(const float4*)(wpv + 512);
            float4 wv3 = *(const float4*)(wpv + 768);
            float am = 0.f, av = 0.f;
            am = fmaf(hr0.x, wm0.x, am); am = fmaf(hr0.y, wm0.y, am);
            am = fmaf(hr0.z, wm0.z, am); am = fmaf(hr0.w, wm0.w, am);
            av = fmaf(hr0.x, wv0.x, av); av = fmaf(hr0.y, wv0.y, av);
            av = fmaf(hr0.z, wv0.z, av); av = fmaf(hr0.w, wv0.w, av);
            am = fmaf(hr1.x, wm1.x, am); am = fmaf(hr1.y, wm1.y, am);
            am = fmaf(hr1.z, wm1.z, am); am = fmaf(hr1.w, wm1.w, am);
            av = fmaf(hr1.x, wv1.x, av); av = fmaf(hr1.y, wv1.y, av);
            av = fmaf(hr1.z, wv1.z, av); av = fmaf(hr1.w, wv1.w, av);
            am = fmaf(hr2.x, wm2.x, am); am = fmaf(hr2.y, wm2.y, am);
            am = fmaf(hr2.z, wm2.z, am); am = fmaf(hr2.w, wm2.w, am);
            av = fmaf(hr2.x, wv2.x, av); av = fmaf(hr2.y, wv2.y, av);
            av = fmaf(hr2.z, wv2.z, av); av = fmaf(hr2.w, wv2.w, av);
            am = fmaf(hr3.x, wm3.x, am); am = fmaf(hr3.y, wm3.y, am);
            am = fmaf(hr3.z, wm3.z, am); am = fmaf(hr3.w, wm3.w, am);
            av = fmaf(hr3.x, wv3.x, av); av = fmaf(hr3.y, wv3.y, av);
            av = fmaf(hr3.z, wv3.z, av); av = fmaf(hr3.w, wv3.w, av);
#pragma unroll
            for (int s = 32; s; s >>= 1) {
                am += __shfl_xor(am, s, 64);
                av += __shfl_xor(av, s, 64);
            }
            if (l == 0) {
                if (o < 48) {
                    float umu = tanhf(am + bum[o]);
                    float uvar = expf(fmaxf(av + buv[o], -6.f));   // threshold(-6,-6)
                    u_raw[o] = umu + uvar * eps_u[b * 48 + o];
                } else {
                    int n = o - 48;
                    float gmu = tanhf(am + bgm[n]);
                    float gpre = av + bgv[n];
                    float gvar = expf(gpre > -6.f ? gpre : 6.f);   // threshold(-6,6)
                    u_raw[o] = gmu + gvar * eps_g[b * 3 + n];
                }
            }
        }
    }
    __syncthreads();

    // ---- compositing setup ----
    if (tid < 16) {
        float ang = u_raw[tid * 3 + 0];
        float tx = u_raw[tid * 3 + 1], ty = u_raw[tid * 3 + 2];
        pc[tid] = cosf(ang);
        psn[tid] = sinf(ang);
        ptx[tid] = tx;
        pty[tid] = ty;
        float ax = fminf(fmaxf(32.f * tx, -16384.f), 16384.f);
        float fax = floorf(ax);
        pwx[tid] = ax - fax;
        pix[tid] = (int)fax;
        float ay = fminf(fmaxf(32.f * ty, -16384.f), 16384.f);
        float fay = floorf(ay);
        pwy[tid] = ay - fay;
        piy[tid] = (int)fay;
    }
    __syncthreads();

    int j = tid & 63;
    int i0 = (tid >> 6) * 4;
    float xnv = (float)(2 * j + 1) * (1.f / 64.f) - 1.f;
    float ynv0 = (float)(2 * i0 + 1) * (1.f / 64.f) - 1.f;

    float num[4] = {}, den[4] = {};

    // ---- p-loop: NO barriers, M plane read direct from global (L2) ----
    for (int p = 0; p < 16; p++) {
        int dx = 8 * (p & 3) - 12;
        int dy = 8 * (p >> 2) - 12;
        float c = pc[p], s = psn[p], tx = ptx[p], ty = pty[p];
        float wx = pwx[p], wy = pwy[p];
        int ix = pix[p], iy = piy[p];
        int iY = iy + dy;

        int x0 = j + ix;
        int X = x0 + dx;
        bool vc0 = ((unsigned)x0 < 64u) && ((unsigned)X < 64u);
        bool vc1 = ((unsigned)(x0 + 1) < 64u) && ((unsigned)(X + 1) < 64u);
        float w0 = vc0 ? (1.f - wx) : 0.f;
        float w1 = vc1 ? wx : 0.f;
        int Xc0 = min(max(X, 0), 63);
        int Xc1 = min(max(X + 1, 0), 63);

        const float* pl = Mb + ((size_t)p << 12);
        float R[5];
#pragma unroll
        for (int r = 0; r < 5; r++) {
            int i = i0 + r;
            int ri = i + iY;
            bool vr = ((unsigned)(i + iy) < 64u) && ((unsigned)ri < 64u);
            int ric = min(max(ri, 0), 63);
            const float* row = pl + (ric << 6);
            float val = fmaf(w0, row[Xc0], w1 * row[Xc1]);
            R[r] = vr ? val : 0.f;
        }

        float gx0 = fmaf(-s, ynv0, fmaf(c, xnv, tx));
        float gy0 = fmaf(c, ynv0, fmaf(s, xnv, ty));
        float xs = fmaf(gx0, 32.f, 31.5f);
        float ysv = fmaf(gy0, 32.f, 31.5f);
        int ox = 24 - dx, oy = 24 - dy;
        float oxf = (float)ox, oyf = (float)oy;
        const float* pp = patch + (p << 8);
#pragma unroll
        for (int r = 0; r < 4; r++) {
            float km = fmaf(wy, R[r + 1] - R[r], R[r]);
            den[r] += km;

            if (xs >= oxf - 1.f && xs < oxf + 16.f &&
                ysv >= oyf - 1.f && ysv < oyf + 16.f) {
                float xf = floorf(xs), yf = floorf(ysv);
                float wxx = xs - xf, wyy = ysv - yf;
                int a0 = (int)yf - oy;
                int b0c = (int)xf - ox;
                float v00 = 0.f, v10 = 0.f, v01 = 0.f, v11 = 0.f;
                if ((unsigned)a0 < 16u) {
                    const float* pr = pp + a0 * 16;
                    if ((unsigned)b0c < 16u) v00 = pr[b0c];
                    if ((unsigned)(b0c + 1) < 16u) v10 = pr[b0c + 1];
                }
                if ((unsigned)(a0 + 1) < 16u) {
                    const float* pr = pp + (a0 + 1) * 16;
                    if ((unsigned)b0c < 16u) v01 = pr[b0c];
                    if ((unsigned)(b0c + 1) < 16u) v11 = pr[b0c + 1];
                }
                float top = fmaf(wxx, v10 - v00, v00);
                float bot = fmaf(wxx, v11 - v01, v01);
                float xp = fmaf(wyy, bot - top, top);
                num[r] = fmaf(xp, km, num[r]);
            }
            xs -= s;   // d(xs)/d(row) = -s
            ysv += c;  // d(ys)/d(row) = +c
        }
    }

#pragma unroll
    for (int r = 0; r < 4; r++) {
        float d = (den[r] == 0.f) ? 1.f : den[r];
        xl[(i0 + r) * 64 + j] = num[r] / d;
    }
    __syncthreads();

    // ---- global gu transform (fused) ----
    float ang = u_raw[48], gtx = u_raw[49], gty = u_raw[50];
    float cg = cosf(ang), sg = sinf(ang);
    float* ob = out + ((size_t)b << 12);
#pragma unroll
    for (int r = 0; r < 4; r++) {
        int i = i0 + r;
        float ynv = (float)(2 * i + 1) * (1.f / 64.f) - 1.f;
        float gx = cg * xnv - sg * ynv + gtx;
        float gy = sg * xnv + cg * ynv + gty;
        gx = fminf(fmaxf(gx, -8.f), 8.f);
        gy = fminf(fmaxf(gy, -8.f), 8.f);
        float xs = fmaf(gx, 32.f, 31.5f);
        float ysv = fmaf(gy, 32.f, 31.5f);
        float xf = floorf(xs), yf = floorf(ysv);
        float wx = xs - xf, wy = ysv - yf;
        int x0 = (int)xf, y0 = (int)yf;
        float v00 = 0.f, v10 = 0.f, v01 = 0.f, v11 = 0.f;
        bool vx0 = (unsigned)x0 < 64u, vx1 = (unsigned)(x0 + 1) < 64u;
        if ((unsigned)y0 < 64u) {
            const float* row = xl + y0 * 64;
            if (vx0) v00 = row[x0];
            if (vx1) v10 = row[x0 + 1];
        }
        if ((unsigned)(y0 + 1) < 64u) {
            const float* row = xl + (y0 + 1) * 64;
            if (vx0) v01 = row[x0];
            if (vx1) v11 = row[x0 + 1];
        }
        float top = fmaf(wx, v10 - v00, v00);
        float bot = fmaf(wx, v11 - v01, v01);
        ob[i * 64 + j] = fmaf(wy, bot - top, top);
    }
}

// ---------------------------------------------------------------------------
extern "C" void kernel_launch(void* const* d_in, const int* in_sizes, int n_in,
                              void* d_out, int out_size, void* d_ws, size_t ws_size,
                              hipStream_t stream)
{
    (void)in_sizes; (void)n_in; (void)out_size; (void)ws_size;
    const float* inputs = (const float*)d_in[0];
    const float* W1  = (const float*)d_in[1];
    const float* b1  = (const float*)d_in[2];
    const float* W2  = (const float*)d_in[3];
    const float* b2  = (const float*)d_in[4];
    const float* Wum = (const float*)d_in[5];
    const float* bum = (const float*)d_in[6];
    const float* Wuv = (const float*)d_in[7];
    const float* buv = (const float*)d_in[8];
    const float* Wgm = (const float*)d_in[9];
    const float* bgm = (const float*)d_in[10];
    const float* Wgv = (const float*)d_in[11];
    const float* bgv = (const float*)d_in[12];
    const float* Wz  = (const float*)d_in[13];
    const float* Mm  = (const float*)d_in[14];
    const float* eps_u = (const float*)d_in[15];
    const float* eps_g = (const float*)d_in[16];

    float* ws = (float*)d_ws;
    float* psum      = ws;                     // 8 x 262144 floats
    float* parts_buf = psum + 8 * PSUM_STRIDE; // 4,096
    float* WTh_buf   = parts_buf + 4096;       // 104,448
    unsigned short* us = (unsigned short*)(WTh_buf + 104448);
    unsigned short* Ahi   = us;                 // 1,048,576
    unsigned short* Alo   = Ahi + 1048576;
    unsigned short* W1Thi = Alo + 1048576;      // 4,194,304
    unsigned short* W1Tlo = W1Thi + 4194304;
    unsigned short* W2Thi = W1Tlo + 4194304;    // 1,048,576
    unsigned short* W2Tlo = W2Thi + 1048576;
    unsigned short* H1hi  = W2Tlo + 1048576;    // 262,144
    unsigned short* H1lo  = H1hi + 262144;

    // Critical-path preprocessing: W1 transpose-split + input convert
    prepA<<<5120, 256, 0, stream>>>(inputs, W1, Ahi, Alo, W1Thi, W1Tlo);

    // MLP layer 1: [256,4096] @ [4096,1024], bf16x3 MFMA split-K=8
    gemm_bf16x3<<<dim3(16, 4, SPLITK), 256, 0, stream>>>(Ahi, Alo, W1Thi, W1Tlo,
                                                         psum, 4096, 4096 / SPLITK);
    // Layer-1 reduce + the non-critical prep (W2T, WT, parts)
    reduce_plus<<<1704, 256, 0, stream>>>(psum, b1, H1hi, H1lo,
                                          W2, W2Thi, W2Tlo,
                                          Wum, Wuv, Wgm, Wgv, Wz,
                                          WTh_buf, parts_buf);
    // MLP layer 2: [256,1024] @ [1024,1024], split-K=8
    gemm_bf16x3<<<dim3(16, 4, SPLITK), 256, 0, stream>>>(H1hi, H1lo, W2Thi, W2Tlo,
                                                         psum, 1024, 1024 / SPLITK);
    // Heads + compositing + global transform -> out [256,1,64,64]
    composite_direct<<<256, 1024, 0, stream>>>(psum, b2, WTh_buf, bum, buv,
                                               bgm, bgv, eps_u, eps_g,
                                               Mm, parts_buf, (float*)d_out);
}

// Round 8
// 196.297 us; speedup vs baseline: 1.0440x; 1.0219x over previous
//
#include <hip/hip_runtime.h>
#include <math.h>

// Problem constants: B=256, H=W=64, P=16, PH=PW=16, ZD=32, HD=1024, UD=3, IN=4096
#define SPLITK 8
#define PSUM_STRIDE 262144   // 256*1024

typedef __bf16 bf16x8 __attribute__((ext_vector_type(8)));
typedef float  f32x16 __attribute__((ext_vector_type(16)));

__device__ __forceinline__ unsigned short bf16rne(float x) {
    unsigned int u = __float_as_uint(x);
    unsigned int r = u + 0x7FFFu + ((u >> 16) & 1u);
    return (unsigned short)(r >> 16);
}
__device__ __forceinline__ float bf16tof(unsigned short h) {
    return __uint_as_float(((unsigned int)h) << 16);
}

// ---------------------------------------------------------------------------
// prep_all: fused independent preprocessing.  [r1/r3-proven: best prep combo]
//  [0,4096)     : W1 -> W1T{hi,lo} transposed split (32x32 tiles)
//  [4096,5120)  : inputs fp32 -> Ahi/Alo bf16 split, float4-vectorized
//  [5120,6144)  : W2 -> W2T{hi,lo}
//  [6144,6552)  : head weights -> k-major WT[102][1024] fp32
//  [6552,6568)  : parts = sigmoid(colsum Wz)
// ---------------------------------------------------------------------------
__global__ __launch_bounds__(256) void prep_all(
    const float* __restrict__ inputs,
    const float* __restrict__ W1, const float* __restrict__ W2,
    const float* __restrict__ Wum, const float* __restrict__ Wuv,
    const float* __restrict__ Wgm, const float* __restrict__ Wgv,
    const float* __restrict__ Wz,
    unsigned short* __restrict__ Ahi, unsigned short* __restrict__ Alo,
    unsigned short* __restrict__ W1Thi, unsigned short* __restrict__ W1Tlo,
    unsigned short* __restrict__ W2Thi, unsigned short* __restrict__ W2Tlo,
    float* __restrict__ WT, float* __restrict__ partsb)
{
    __shared__ float t[32][33];
    int bid = blockIdx.x;
    int tid = threadIdx.x;
    if (bid < 4096 || (bid >= 5120 && bid < 6144)) {
        const float* W = (bid < 4096) ? W1 : W2;
        unsigned short* Thi = (bid < 4096) ? W1Thi : W2Thi;
        unsigned short* Tlo = (bid < 4096) ? W1Tlo : W2Tlo;
        int K = (bid < 4096) ? 4096 : 1024;
        int b2 = (bid < 4096) ? bid : (bid - 5120);
        int n0 = (b2 & 31) * 32, k0 = (b2 >> 5) * 32;
        int c = tid & 31, r0 = tid >> 5;
#pragma unroll
        for (int i = 0; i < 4; i++)
            t[r0 + 8 * i][c] = W[(size_t)(k0 + r0 + 8 * i) * 1024 + n0 + c];
        __syncthreads();
        int kk = tid & 31, n1 = tid >> 5;
#pragma unroll
        for (int i = 0; i < 4; i++) {
            float x = t[kk][n1 + 8 * i];
            unsigned short h = bf16rne(x);
            unsigned short l = bf16rne(x - bf16tof(h));
            size_t o = (size_t)(n0 + n1 + 8 * i) * K + k0 + kk;
            Thi[o] = h;
            Tlo[o] = l;
        }
    } else if (bid < 5120) {
        int id = ((bid - 4096) * 256 + tid) * 4;
        float4 x = *(const float4*)(inputs + id);
        ushort4 h, l;
        h.x = bf16rne(x.x); l.x = bf16rne(x.x - bf16tof(h.x));
        h.y = bf16rne(x.y); l.y = bf16rne(x.y - bf16tof(h.y));
        h.z = bf16rne(x.z); l.z = bf16rne(x.z - bf16tof(h.z));
        h.w = bf16rne(x.w); l.w = bf16rne(x.w - bf16tof(h.w));
        *(ushort4*)(Ahi + id) = h;
        *(ushort4*)(Alo + id) = l;
    } else if (bid < 6552) {
        int id = (bid - 6144) * 256 + tid;
        int o = id >> 10;
        int k = id & 1023;
        float v;
        if (o < 48)       v = Wum[k * 48 + o];
        else if (o < 96)  v = Wuv[k * 48 + (o - 48)];
        else if (o < 99)  v = Wgm[k * 3 + (o - 96)];
        else              v = Wgv[k * 3 + (o - 99)];
        WT[id] = v;
    } else {
        int idx = (bid - 6552) * 256 + tid;
        float s = 0.f;
#pragma unroll
        for (int z = 0; z < 32; z++) s += Wz[z * 4096 + idx];
        partsb[idx] = 1.f / (1.f + expf(-s));
    }
}

// ---------------------------------------------------------------------------
// GEMM bf16x3: 64x64 tile, 4 waves, 32x32x16 MFMA, XOR-swizzled LDS. [r1-proven]
// ---------------------------------------------------------------------------
__global__ __launch_bounds__(256) void gemm_bf16x3(
    const unsigned short* __restrict__ Ahi, const unsigned short* __restrict__ Alo,
    const unsigned short* __restrict__ Bhi, const unsigned short* __restrict__ Blo,
    float* __restrict__ psum, int K, int kchunk)
{
    __shared__ unsigned short Ah[4096], Al[4096], Bh[4096], Bl[4096];
    int tid = threadIdx.x;
    int n0 = blockIdx.x * 64, m0 = blockIdx.y * 64;
    int kb = blockIdx.z * kchunk;
    int wid = tid >> 6, lane = tid & 63;
    int wm = wid & 1, wn = wid >> 1;
    int lr = lane & 31, hi = lane >> 5;

    int r0 = tid >> 3, ch0 = tid & 7;
    int r1 = (tid + 256) >> 3, ch1 = (tid + 256) & 7;
    int l0 = r0 * 64 + 8 * (ch0 ^ (r0 & 7));
    int l1 = r1 * 64 + 8 * (ch1 ^ (r1 & 7));
    size_t ga0 = (size_t)(m0 + r0) * K + kb + ch0 * 8;
    size_t ga1 = (size_t)(m0 + r1) * K + kb + ch1 * 8;
    size_t gb0 = (size_t)(n0 + r0) * K + kb + ch0 * 8;
    size_t gb1 = (size_t)(n0 + r1) * K + kb + ch1 * 8;

    f32x16 acc_hh = {}, acc_hl = {}, acc_lh = {};

    int nkt = kchunk >> 6;
    uint4 vah0, vah1, val0, val1, vbh0, vbh1, vbl0, vbl1;
    vah0 = *(const uint4*)(Ahi + ga0);
    vah1 = *(const uint4*)(Ahi + ga1);
    val0 = *(const uint4*)(Alo + ga0);
    val1 = *(const uint4*)(Alo + ga1);
    vbh0 = *(const uint4*)(Bhi + gb0);
    vbh1 = *(const uint4*)(Bhi + gb1);
    vbl0 = *(const uint4*)(Blo + gb0);
    vbl1 = *(const uint4*)(Blo + gb1);

    int basea = (wm * 32 + lr) * 64;
    int baseb = (wn * 32 + lr) * 64;
    int sw = lr & 7;

    for (int kt = 0; kt < nkt; kt++) {
        __syncthreads();
        *(uint4*)(Ah + l0) = vah0;
        *(uint4*)(Ah + l1) = vah1;
        *(uint4*)(Al + l0) = val0;
        *(uint4*)(Al + l1) = val1;
        *(uint4*)(Bh + l0) = vbh0;
        *(uint4*)(Bh + l1) = vbh1;
        *(uint4*)(Bl + l0) = vbl0;
        *(uint4*)(Bl + l1) = vbl1;
        __syncthreads();
        if (kt + 1 < nkt) {
            size_t o = (size_t)(kt + 1) * 64;
            vah0 = *(const uint4*)(Ahi + ga0 + o);
            vah1 = *(const uint4*)(Ahi + ga1 + o);
            val0 = *(const uint4*)(Alo + ga0 + o);
            val1 = *(const uint4*)(Alo + ga1 + o);
            vbh0 = *(const uint4*)(Bhi + gb0 + o);
            vbh1 = *(const uint4*)(Bhi + gb1 + o);
            vbl0 = *(const uint4*)(Blo + gb0 + o);
            vbl1 = *(const uint4*)(Blo + gb1 + o);
        }
#pragma unroll
        for (int s = 0; s < 4; s++) {
            int cidx = 8 * (((s << 1) + hi) ^ sw);
            bf16x8 afh = *(const bf16x8*)(Ah + basea + cidx);
            bf16x8 afl = *(const bf16x8*)(Al + basea + cidx);
            bf16x8 bfh = *(const bf16x8*)(Bh + baseb + cidx);
            bf16x8 bfl = *(const bf16x8*)(Bl + baseb + cidx);
            acc_hh = __builtin_amdgcn_mfma_f32_32x32x16_bf16(afh, bfh, acc_hh, 0, 0, 0);
            acc_hl = __builtin_amdgcn_mfma_f32_32x32x16_bf16(afh, bfl, acc_hl, 0, 0, 0);
            acc_lh = __builtin_amdgcn_mfma_f32_32x32x16_bf16(afl, bfh, acc_lh, 0, 0, 0);
        }
    }

    float* op = psum + (size_t)blockIdx.z * PSUM_STRIDE;
    int colg = n0 + wn * 32 + lr;
#pragma unroll
    for (int r = 0; r < 16; r++) {
        int rowl = (r & 3) + 8 * (r >> 2) + 4 * hi;
        op[(size_t)(m0 + wm * 32 + rowl) * 1024 + colg] = acc_hh[r] + acc_hl[r] + acc_lh[r];
    }
}

// ---------------------------------------------------------------------------
// Reduce layer-1 partials + bias + relu -> bf16 hi/lo split.  [r1/r3-proven]
// ---------------------------------------------------------------------------
__global__ __launch_bounds__(256) void reduce_bias_relu_split(
    const float* __restrict__ psum, const float* __restrict__ bias,
    unsigned short* __restrict__ hi, unsigned short* __restrict__ lo)
{
    int i = (blockIdx.x * 256 + threadIdx.x) * 4;
    float4 v = *(const float4*)(psum + i);
#pragma unroll
    for (int s = 1; s < SPLITK; s++) {
        float4 t = *(const float4*)(psum + (size_t)s * PSUM_STRIDE + i);
        v.x += t.x; v.y += t.y; v.z += t.z; v.w += t.w;
    }
    float4 bb = *(const float4*)(bias + (i & 1023));
    v.x = fmaxf(v.x + bb.x, 0.f);
    v.y = fmaxf(v.y + bb.y, 0.f);
    v.z = fmaxf(v.z + bb.z, 0.f);
    v.w = fmaxf(v.w + bb.w, 0.f);
    ushort4 h, l;
    h.x = bf16rne(v.x); l.x = bf16rne(v.x - bf16tof(h.x));
    h.y = bf16rne(v.y); l.y = bf16rne(v.y - bf16tof(h.y));
    h.z = bf16rne(v.z); l.z = bf16rne(v.z - bf16tof(h.z));
    h.w = bf16rne(v.w); l.w = bf16rne(v.w - bf16tof(h.w));
    *(ushort4*)(hi + i) = h;
    *(ushort4*)(lo + i) = l;
}

// ---------------------------------------------------------------------------
// composite_direct: M read DIRECTLY from global (L2-resident), no plane LDS,
// no staging, ZERO barriers in the p-loop.  [r7-proven: dropped below 40 us]
// ---------------------------------------------------------------------------
__global__ __launch_bounds__(1024) void composite_direct(
    const float* __restrict__ psum, const float* __restrict__ b2,
    const float* __restrict__ WT,
    const float* __restrict__ bum, const float* __restrict__ buv,
    const float* __restrict__ bgm, const float* __restrict__ bgv,
    const float* __restrict__ eps_u, const float* __restrict__ eps_g,
    const float* __restrict__ M, const float* __restrict__ parts,
    float* __restrict__ out)
{
    __shared__ float patch[4096];   // 16 KB
    __shared__ float xl[4096];      // 16 KB
    __shared__ float h2[1024];      // 4 KB
    __shared__ float u_raw[51];
    __shared__ float pc[16], psn[16], ptx[16], pty[16], pwx[16], pwy[16];
    __shared__ int pix[16], piy[16];
    int b = blockIdx.x;
    int tid = threadIdx.x;

    const float* Mb = M + ((size_t)(b * 16) << 12);

    // ---- heads prologue: layer-2 reduce for row b ----
    {
        float v = psum[(size_t)b * 1024 + tid];
#pragma unroll
        for (int s = 1; s < SPLITK; s++)
            v += psum[(size_t)s * PSUM_STRIDE + (size_t)b * 1024 + tid];
        h2[tid] = fmaxf(v + b2[tid], 0.f);
    }
    for (int i = tid; i < 4096; i += 1024) patch[i] = parts[i];
    __syncthreads();

    // ---- head matvecs (same summation order as heads_v3) ----
    {
        int w = tid >> 6, l = tid & 63;
        const float4* h4 = (const float4*)h2;
        float4 hr0 = h4[l], hr1 = h4[64 + l], hr2 = h4[128 + l], hr3 = h4[192 + l];
        for (int o = w; o < 51; o += 16) {
            int rm = (o < 48) ? o : (48 + o);
            int rv = (o < 48) ? (o + 48) : (51 + o);
            const float* wpm = WT + rm * 1024 + l * 4;
            const float* wpv = WT + rv * 1024 + l * 4;
            float4 wm0 = *(const float4*)(wpm);
            float4 wm1 = *(const float4*)(wpm + 256);
            float4 wm2 = *(const float4*)(wpm + 512);
            float4 wm3 = *(const float4*)(wpm + 768);
            float4 wv0 = *(const float4*)(wpv);
            float4 wv1 = *(const float4*)(wpv + 256);
            float4 wv2 = *(const float4*)(wpv + 512);
            float4 wv3 = *(const float4*)(wpv + 768);
            float am = 0.f, av = 0.f;
            am = fmaf(hr0.x, wm0.x, am); am = fmaf(hr0.y, wm0.y, am);
            am = fmaf(hr0.z, wm0.z, am); am = fmaf(hr0.w, wm0.w, am);
            av = fmaf(hr0.x, wv0.x, av); av = fmaf(hr0.y, wv0.y, av);
            av = fmaf(hr0.z, wv0.z, av); av = fmaf(hr0.w, wv0.w, av);
            am = fmaf(hr1.x, wm1.x, am); am = fmaf(hr1.y, wm1.y, am);
            am = fmaf(hr1.z, wm1.z, am); am = fmaf(hr1.w, wm1.w, am);
            av = fmaf(hr1.x, wv1.x, av); av = fmaf(hr1.y, wv1.y, av);
            av = fmaf(hr1.z, wv1.z, av); av = fmaf(hr1.w, wv1.w, av);
            am = fmaf(hr2.x, wm2.x, am); am = fmaf(hr2.y, wm2.y, am);
            am = fmaf(hr2.z, wm2.z, am); am = fmaf(hr2.w, wm2.w, am);
            av = fmaf(hr2.x, wv2.x, av); av = fmaf(hr2.y, wv2.y, av);
            av = fmaf(hr2.z, wv2.z, av); av = fmaf(hr2.w, wv2.w, av);
            am = fmaf(hr3.x, wm3.x, am); am = fmaf(hr3.y, wm3.y, am);
            am = fmaf(hr3.z, wm3.z, am); am = fmaf(hr3.w, wm3.w, am);
            av = fmaf(hr3.x, wv3.x, av); av = fmaf(hr3.y, wv3.y, av);
            av = fmaf(hr3.z, wv3.z, av); av = fmaf(hr3.w, wv3.w, av);
#pragma unroll
            for (int s = 32; s; s >>= 1) {
                am += __shfl_xor(am, s, 64);
                av += __shfl_xor(av, s, 64);
            }
            if (l == 0) {
                if (o < 48) {
                    float umu = tanhf(am + bum[o]);
                    float uvar = expf(fmaxf(av + buv[o], -6.f));   // threshold(-6,-6)
                    u_raw[o] = umu + uvar * eps_u[b * 48 + o];
                } else {
                    int n = o - 48;
                    float gmu = tanhf(am + bgm[n]);
                    float gpre = av + bgv[n];
                    float gvar = expf(gpre > -6.f ? gpre : 6.f);   // threshold(-6,6)
                    u_raw[o] = gmu + gvar * eps_g[b * 3 + n];
                }
            }
        }
    }
    __syncthreads();

    // ---- compositing setup ----
    if (tid < 16) {
        float ang = u_raw[tid * 3 + 0];
        float tx = u_raw[tid * 3 + 1], ty = u_raw[tid * 3 + 2];
        pc[tid] = cosf(ang);
        psn[tid] = sinf(ang);
        ptx[tid] = tx;
        pty[tid] = ty;
        float ax = fminf(fmaxf(32.f * tx, -16384.f), 16384.f);
        float fax = floorf(ax);
        pwx[tid] = ax - fax;
        pix[tid] = (int)fax;
        float ay = fminf(fmaxf(32.f * ty, -16384.f), 16384.f);
        float fay = floorf(ay);
        pwy[tid] = ay - fay;
        piy[tid] = (int)fay;
    }
    __syncthreads();

    int j = tid & 63;
    int i0 = (tid >> 6) * 4;
    float xnv = (float)(2 * j + 1) * (1.f / 64.f) - 1.f;
    float ynv0 = (float)(2 * i0 + 1) * (1.f / 64.f) - 1.f;

    float num[4] = {}, den[4] = {};

    // ---- p-loop: NO barriers, M plane read direct from global (L2) ----
    for (int p = 0; p < 16; p++) {
        int dx = 8 * (p & 3) - 12;
        int dy = 8 * (p >> 2) - 12;
        float c = pc[p], s = psn[p], tx = ptx[p], ty = pty[p];
        float wx = pwx[p], wy = pwy[p];
        int ix = pix[p], iy = piy[p];
        int iY = iy + dy;

        int x0 = j + ix;
        int X = x0 + dx;
        bool vc0 = ((unsigned)x0 < 64u) && ((unsigned)X < 64u);
        bool vc1 = ((unsigned)(x0 + 1) < 64u) && ((unsigned)(X + 1) < 64u);
        float w0 = vc0 ? (1.f - wx) : 0.f;
        float w1 = vc1 ? wx : 0.f;
        int Xc0 = min(max(X, 0), 63);
        int Xc1 = min(max(X + 1, 0), 63);

        const float* pl = Mb + ((size_t)p << 12);
        float R[5];
#pragma unroll
        for (int r = 0; r < 5; r++) {
            int i = i0 + r;
            int ri = i + iY;
            bool vr = ((unsigned)(i + iy) < 64u) && ((unsigned)ri < 64u);
            int ric = min(max(ri, 0), 63);
            const float* row = pl + (ric << 6);
            float val = fmaf(w0, row[Xc0], w1 * row[Xc1]);
            R[r] = vr ? val : 0.f;
        }

        float gx0 = fmaf(-s, ynv0, fmaf(c, xnv, tx));
        float gy0 = fmaf(c, ynv0, fmaf(s, xnv, ty));
        float xs = fmaf(gx0, 32.f, 31.5f);
        float ysv = fmaf(gy0, 32.f, 31.5f);
        int ox = 24 - dx, oy = 24 - dy;
        float oxf = (float)ox, oyf = (float)oy;
        const float* pp = patch + (p << 8);
#pragma unroll
        for (int r = 0; r < 4; r++) {
            float km = fmaf(wy, R[r + 1] - R[r], R[r]);
            den[r] += km;

            if (xs >= oxf - 1.f && xs < oxf + 16.f &&
                ysv >= oyf - 1.f && ysv < oyf + 16.f) {
                float xf = floorf(xs), yf = floorf(ysv);
                float wxx = xs - xf, wyy = ysv - yf;
                int a0 = (int)yf - oy;
                int b0c = (int)xf - ox;
                float v00 = 0.f, v10 = 0.f, v01 = 0.f, v11 = 0.f;
                if ((unsigned)a0 < 16u) {
                    const float* pr = pp + a0 * 16;
                    if ((unsigned)b0c < 16u) v00 = pr[b0c];
                    if ((unsigned)(b0c + 1) < 16u) v10 = pr[b0c + 1];
                }
                if ((unsigned)(a0 + 1) < 16u) {
                    const float* pr = pp + (a0 + 1) * 16;
                    if ((unsigned)b0c < 16u) v01 = pr[b0c];
                    if ((unsigned)(b0c + 1) < 16u) v11 = pr[b0c + 1];
                }
                float top = fmaf(wxx, v10 - v00, v00);
                float bot = fmaf(wxx, v11 - v01, v01);
                float xp = fmaf(wyy, bot - top, top);
                num[r] = fmaf(xp, km, num[r]);
            }
            xs -= s;   // d(xs)/d(row) = -s
            ysv += c;  // d(ys)/d(row) = +c
        }
    }

#pragma unroll
    for (int r = 0; r < 4; r++) {
        float d = (den[r] == 0.f) ? 1.f : den[r];
        xl[(i0 + r) * 64 + j] = num[r] / d;
    }
    __syncthreads();

    // ---- global gu transform (fused) ----
    float ang = u_raw[48], gtx = u_raw[49], gty = u_raw[50];
    float cg = cosf(ang), sg = sinf(ang);
    float* ob = out + ((size_t)b << 12);
#pragma unroll
    for (int r = 0; r < 4; r++) {
        int i = i0 + r;
        float ynv = (float)(2 * i + 1) * (1.f / 64.f) - 1.f;
        float gx = cg * xnv - sg * ynv + gtx;
        float gy = sg * xnv + cg * ynv + gty;
        gx = fminf(fmaxf(gx, -8.f), 8.f);
        gy = fminf(fmaxf(gy, -8.f), 8.f);
        float xs = fmaf(gx, 32.f, 31.5f);
        float ysv = fmaf(gy, 32.f, 31.5f);
        float xf = floorf(xs), yf = floorf(ysv);
        float wx = xs - xf, wy = ysv - yf;
        int x0 = (int)xf, y0 = (int)yf;
        float v00 = 0.f, v10 = 0.f, v01 = 0.f, v11 = 0.f;
        bool vx0 = (unsigned)x0 < 64u, vx1 = (unsigned)(x0 + 1) < 64u;
        if ((unsigned)y0 < 64u) {
            const float* row = xl + y0 * 64;
            if (vx0) v00 = row[x0];
            if (vx1) v10 = row[x0 + 1];
        }
        if ((unsigned)(y0 + 1) < 64u) {
            const float* row = xl + (y0 + 1) * 64;
            if (vx0) v01 = row[x0];
            if (vx1) v11 = row[x0 + 1];
        }
        float top = fmaf(wx, v10 - v00, v00);
        float bot = fmaf(wx, v11 - v01, v01);
        ob[i * 64 + j] = fmaf(wy, bot - top, top);
    }
}

// ---------------------------------------------------------------------------
extern "C" void kernel_launch(void* const* d_in, const int* in_sizes, int n_in,
                              void* d_out, int out_size, void* d_ws, size_t ws_size,
                              hipStream_t stream)
{
    (void)in_sizes; (void)n_in; (void)out_size; (void)ws_size;
    const float* inputs = (const float*)d_in[0];
    const float* W1  = (const float*)d_in[1];
    const float* b1  = (const float*)d_in[2];
    const float* W2  = (const float*)d_in[3];
    const float* b2  = (const float*)d_in[4];
    const float* Wum = (const float*)d_in[5];
    const float* bum = (const float*)d_in[6];
    const float* Wuv = (const float*)d_in[7];
    const float* buv = (const float*)d_in[8];
    const float* Wgm = (const float*)d_in[9];
    const float* bgm = (const float*)d_in[10];
    const float* Wgv = (const float*)d_in[11];
    const float* bgv = (const float*)d_in[12];
    const float* Wz  = (const float*)d_in[13];
    const float* Mm  = (const float*)d_in[14];
    const float* eps_u = (const float*)d_in[15];
    const float* eps_g = (const float*)d_in[16];

    float* ws = (float*)d_ws;
    float* psum      = ws;                     // 8 x 262144 floats
    float* parts_buf = psum + 8 * PSUM_STRIDE; // 4,096
    float* WTh_buf   = parts_buf + 4096;       // 104,448
    unsigned short* us = (unsigned short*)(WTh_buf + 104448);
    unsigned short* Ahi   = us;                 // 1,048,576
    unsigned short* Alo   = Ahi + 1048576;
    unsigned short* W1Thi = Alo + 1048576;      // 4,194,304
    unsigned short* W1Tlo = W1Thi + 4194304;
    unsigned short* W2Thi = W1Tlo + 4194304;    // 1,048,576
    unsigned short* W2Tlo = W2Thi + 1048576;
    unsigned short* H1hi  = W2Tlo + 1048576;    // 262,144
    unsigned short* H1lo  = H1hi + 262144;

    // Preprocessing (single fused kernel -- r3-proven faster than the split)
    prep_all<<<6568, 256, 0, stream>>>(inputs, W1, W2, Wum, Wuv, Wgm, Wgv, Wz,
                                       Ahi, Alo, W1Thi, W1Tlo, W2Thi, W2Tlo,
                                       WTh_buf, parts_buf);

    // MLP layer 1: [256,4096] @ [4096,1024], bf16x3 MFMA split-K=8
    gemm_bf16x3<<<dim3(16, 4, SPLITK), 256, 0, stream>>>(Ahi, Alo, W1Thi, W1Tlo,
                                                         psum, 4096, 4096 / SPLITK);
    reduce_bias_relu_split<<<256, 256, 0, stream>>>(psum, b1, H1hi, H1lo);
    // MLP layer 2: [256,1024] @ [1024,1024], split-K=8
    gemm_bf16x3<<<dim3(16, 4, SPLITK), 256, 0, stream>>>(H1hi, H1lo, W2Thi, W2Tlo,
                                                         psum, 1024, 1024 / SPLITK);
    // Heads + compositing + global transform -> out [256,1,64,64]
    composite_direct<<<256, 1024, 0, stream>>>(psum, b2, WTh_buf, bum, buv,
                                               bgm, bgv, eps_u, eps_g,
                                               Mm, parts_buf, (float*)d_out);
}

// Round 9
// 195.064 us; speedup vs baseline: 1.0506x; 1.0063x over previous
//
#include <hip/hip_runtime.h>
#include <math.h>

// Problem constants: B=256, H=W=64, P=16, PH=PW=16, ZD=32, HD=1024, UD=3, IN=4096
#define SPLITK 8
#define PSUM_STRIDE 262144   // 256*1024

typedef __bf16 bf16x8 __attribute__((ext_vector_type(8)));
typedef float  f32x16 __attribute__((ext_vector_type(16)));

__device__ __forceinline__ unsigned short bf16rne(float x) {
    unsigned int u = __float_as_uint(x);
    unsigned int r = u + 0x7FFFu + ((u >> 16) & 1u);
    return (unsigned short)(r >> 16);
}
__device__ __forceinline__ float bf16tof(unsigned short h) {
    return __uint_as_float(((unsigned int)h) << 16);
}

// ---------------------------------------------------------------------------
// prep_all: fused independent preprocessing.  [r1/r3-proven]
// ---------------------------------------------------------------------------
__global__ __launch_bounds__(256) void prep_all(
    const float* __restrict__ inputs,
    const float* __restrict__ W1, const float* __restrict__ W2,
    const float* __restrict__ Wum, const float* __restrict__ Wuv,
    const float* __restrict__ Wgm, const float* __restrict__ Wgv,
    const float* __restrict__ Wz,
    unsigned short* __restrict__ Ahi, unsigned short* __restrict__ Alo,
    unsigned short* __restrict__ W1Thi, unsigned short* __restrict__ W1Tlo,
    unsigned short* __restrict__ W2Thi, unsigned short* __restrict__ W2Tlo,
    float* __restrict__ WT, float* __restrict__ partsb)
{
    __shared__ float t[32][33];
    int bid = blockIdx.x;
    int tid = threadIdx.x;
    if (bid < 4096 || (bid >= 5120 && bid < 6144)) {
        const float* W = (bid < 4096) ? W1 : W2;
        unsigned short* Thi = (bid < 4096) ? W1Thi : W2Thi;
        unsigned short* Tlo = (bid < 4096) ? W1Tlo : W2Tlo;
        int K = (bid < 4096) ? 4096 : 1024;
        int b2 = (bid < 4096) ? bid : (bid - 5120);
        int n0 = (b2 & 31) * 32, k0 = (b2 >> 5) * 32;
        int c = tid & 31, r0 = tid >> 5;
#pragma unroll
        for (int i = 0; i < 4; i++)
            t[r0 + 8 * i][c] = W[(size_t)(k0 + r0 + 8 * i) * 1024 + n0 + c];
        __syncthreads();
        int kk = tid & 31, n1 = tid >> 5;
#pragma unroll
        for (int i = 0; i < 4; i++) {
            float x = t[kk][n1 + 8 * i];
            unsigned short h = bf16rne(x);
            unsigned short l = bf16rne(x - bf16tof(h));
            size_t o = (size_t)(n0 + n1 + 8 * i) * K + k0 + kk;
            Thi[o] = h;
            Tlo[o] = l;
        }
    } else if (bid < 5120) {
        int id = ((bid - 4096) * 256 + tid) * 4;
        float4 x = *(const float4*)(inputs + id);
        ushort4 h, l;
        h.x = bf16rne(x.x); l.x = bf16rne(x.x - bf16tof(h.x));
        h.y = bf16rne(x.y); l.y = bf16rne(x.y - bf16tof(h.y));
        h.z = bf16rne(x.z); l.z = bf16rne(x.z - bf16tof(h.z));
        h.w = bf16rne(x.w); l.w = bf16rne(x.w - bf16tof(h.w));
        *(ushort4*)(Ahi + id) = h;
        *(ushort4*)(Alo + id) = l;
    } else if (bid < 6552) {
        int id = (bid - 6144) * 256 + tid;
        int o = id >> 10;
        int k = id & 1023;
        float v;
        if (o < 48)       v = Wum[k * 48 + o];
        else if (o < 96)  v = Wuv[k * 48 + (o - 48)];
        else if (o < 99)  v = Wgm[k * 3 + (o - 96)];
        else              v = Wgv[k * 3 + (o - 99)];
        WT[id] = v;
    } else {
        int idx = (bid - 6552) * 256 + tid;
        float s = 0.f;
#pragma unroll
        for (int z = 0; z < 32; z++) s += Wz[z * 4096 + idx];
        partsb[idx] = 1.f / (1.f + expf(-s));
    }
}

// ---------------------------------------------------------------------------
// GEMM bf16x3: 64x64 tile, 4 waves, 32x32x16 MFMA, XOR-swizzled LDS. [r1-proven]
// ---------------------------------------------------------------------------
__global__ __launch_bounds__(256) void gemm_bf16x3(
    const unsigned short* __restrict__ Ahi, const unsigned short* __restrict__ Alo,
    const unsigned short* __restrict__ Bhi, const unsigned short* __restrict__ Blo,
    float* __restrict__ psum, int K, int kchunk)
{
    __shared__ unsigned short Ah[4096], Al[4096], Bh[4096], Bl[4096];
    int tid = threadIdx.x;
    int n0 = blockIdx.x * 64, m0 = blockIdx.y * 64;
    int kb = blockIdx.z * kchunk;
    int wid = tid >> 6, lane = tid & 63;
    int wm = wid & 1, wn = wid >> 1;
    int lr = lane & 31, hi = lane >> 5;

    int r0 = tid >> 3, ch0 = tid & 7;
    int r1 = (tid + 256) >> 3, ch1 = (tid + 256) & 7;
    int l0 = r0 * 64 + 8 * (ch0 ^ (r0 & 7));
    int l1 = r1 * 64 + 8 * (ch1 ^ (r1 & 7));
    size_t ga0 = (size_t)(m0 + r0) * K + kb + ch0 * 8;
    size_t ga1 = (size_t)(m0 + r1) * K + kb + ch1 * 8;
    size_t gb0 = (size_t)(n0 + r0) * K + kb + ch0 * 8;
    size_t gb1 = (size_t)(n0 + r1) * K + kb + ch1 * 8;

    f32x16 acc_hh = {}, acc_hl = {}, acc_lh = {};

    int nkt = kchunk >> 6;
    uint4 vah0, vah1, val0, val1, vbh0, vbh1, vbl0, vbl1;
    vah0 = *(const uint4*)(Ahi + ga0);
    vah1 = *(const uint4*)(Ahi + ga1);
    val0 = *(const uint4*)(Alo + ga0);
    val1 = *(const uint4*)(Alo + ga1);
    vbh0 = *(const uint4*)(Bhi + gb0);
    vbh1 = *(const uint4*)(Bhi + gb1);
    vbl0 = *(const uint4*)(Blo + gb0);
    vbl1 = *(const uint4*)(Blo + gb1);

    int basea = (wm * 32 + lr) * 64;
    int baseb = (wn * 32 + lr) * 64;
    int sw = lr & 7;

    for (int kt = 0; kt < nkt; kt++) {
        __syncthreads();
        *(uint4*)(Ah + l0) = vah0;
        *(uint4*)(Ah + l1) = vah1;
        *(uint4*)(Al + l0) = val0;
        *(uint4*)(Al + l1) = val1;
        *(uint4*)(Bh + l0) = vbh0;
        *(uint4*)(Bh + l1) = vbh1;
        *(uint4*)(Bl + l0) = vbl0;
        *(uint4*)(Bl + l1) = vbl1;
        __syncthreads();
        if (kt + 1 < nkt) {
            size_t o = (size_t)(kt + 1) * 64;
            vah0 = *(const uint4*)(Ahi + ga0 + o);
            vah1 = *(const uint4*)(Ahi + ga1 + o);
            val0 = *(const uint4*)(Alo + ga0 + o);
            val1 = *(const uint4*)(Alo + ga1 + o);
            vbh0 = *(const uint4*)(Bhi + gb0 + o);
            vbh1 = *(const uint4*)(Bhi + gb1 + o);
            vbl0 = *(const uint4*)(Blo + gb0 + o);
            vbl1 = *(const uint4*)(Blo + gb1 + o);
        }
#pragma unroll
        for (int s = 0; s < 4; s++) {
            int cidx = 8 * (((s << 1) + hi) ^ sw);
            bf16x8 afh = *(const bf16x8*)(Ah + basea + cidx);
            bf16x8 afl = *(const bf16x8*)(Al + basea + cidx);
            bf16x8 bfh = *(const bf16x8*)(Bh + baseb + cidx);
            bf16x8 bfl = *(const bf16x8*)(Bl + baseb + cidx);
            acc_hh = __builtin_amdgcn_mfma_f32_32x32x16_bf16(afh, bfh, acc_hh, 0, 0, 0);
            acc_hl = __builtin_amdgcn_mfma_f32_32x32x16_bf16(afh, bfl, acc_hl, 0, 0, 0);
            acc_lh = __builtin_amdgcn_mfma_f32_32x32x16_bf16(afl, bfh, acc_lh, 0, 0, 0);
        }
    }

    float* op = psum + (size_t)blockIdx.z * PSUM_STRIDE;
    int colg = n0 + wn * 32 + lr;
#pragma unroll
    for (int r = 0; r < 16; r++) {
        int rowl = (r & 3) + 8 * (r >> 2) + 4 * hi;
        op[(size_t)(m0 + wm * 32 + rowl) * 1024 + colg] = acc_hh[r] + acc_hl[r] + acc_lh[r];
    }
}

// ---------------------------------------------------------------------------
// Reduce layer-1 partials + bias + relu -> bf16 hi/lo split.  [r1/r3-proven]
// ---------------------------------------------------------------------------
__global__ __launch_bounds__(256) void reduce_bias_relu_split(
    const float* __restrict__ psum, const float* __restrict__ bias,
    unsigned short* __restrict__ hi, unsigned short* __restrict__ lo)
{
    int i = (blockIdx.x * 256 + threadIdx.x) * 4;
    float4 v = *(const float4*)(psum + i);
#pragma unroll
    for (int s = 1; s < SPLITK; s++) {
        float4 t = *(const float4*)(psum + (size_t)s * PSUM_STRIDE + i);
        v.x += t.x; v.y += t.y; v.z += t.z; v.w += t.w;
    }
    float4 bb = *(const float4*)(bias + (i & 1023));
    v.x = fmaxf(v.x + bb.x, 0.f);
    v.y = fmaxf(v.y + bb.y, 0.f);
    v.z = fmaxf(v.z + bb.z, 0.f);
    v.w = fmaxf(v.w + bb.w, 0.f);
    ushort4 h, l;
    h.x = bf16rne(v.x); l.x = bf16rne(v.x - bf16tof(h.x));
    h.y = bf16rne(v.y); l.y = bf16rne(v.y - bf16tof(h.y));
    h.z = bf16rne(v.z); l.z = bf16rne(v.z - bf16tof(h.z));
    h.w = bf16rne(v.w); l.w = bf16rne(v.w - bf16tof(h.w));
    *(ushort4*)(hi + i) = h;
    *(ushort4*)(lo + i) = l;
}

// ---------------------------------------------------------------------------
// composite_direct v2: software-pipelined p-loop.
// r8 counters showed VGPR=40 / VALUBusy=41% -> compiler did NOT hoist the
// 10 M-tap loads across parts; every part ate a full L2 latency.  This
// version splits each part into load_taps(p) (addr calc + 10 tap loads into
// a statically-indexed PTaps struct) and consume(p) (pure VALU, arithmetic
// bit-identical), pipelined 1-deep with unroll-by-2 (no register copies).
// M still read direct from global (L2-resident, r7-proven); no p-loop
// barriers; final gu transform fused.
// ---------------------------------------------------------------------------
struct PTaps {
    float t[10];
    float w0, w1, wy, c, s, tx, ty;
    int iy;
};

__global__ __launch_bounds__(1024) void composite_direct(
    const float* __restrict__ psum, const float* __restrict__ b2,
    const float* __restrict__ WT,
    const float* __restrict__ bum, const float* __restrict__ buv,
    const float* __restrict__ bgm, const float* __restrict__ bgv,
    const float* __restrict__ eps_u, const float* __restrict__ eps_g,
    const float* __restrict__ M, const float* __restrict__ parts,
    float* __restrict__ out)
{
    __shared__ float patch[4096];   // 16 KB
    __shared__ float xl[4096];      // 16 KB
    __shared__ float h2[1024];      // 4 KB
    __shared__ float u_raw[51];
    __shared__ float pc[16], psn[16], ptx[16], pty[16], pwx[16], pwy[16];
    __shared__ int pix[16], piy[16];
    int b = blockIdx.x;
    int tid = threadIdx.x;

    const float* Mb = M + ((size_t)(b * 16) << 12);

    // ---- heads prologue: layer-2 reduce for row b ----
    {
        float v = psum[(size_t)b * 1024 + tid];
#pragma unroll
        for (int s = 1; s < SPLITK; s++)
            v += psum[(size_t)s * PSUM_STRIDE + (size_t)b * 1024 + tid];
        h2[tid] = fmaxf(v + b2[tid], 0.f);
    }
    for (int i = tid; i < 4096; i += 1024) patch[i] = parts[i];
    __syncthreads();

    // ---- head matvecs (same summation order as heads_v3) ----
    {
        int w = tid >> 6, l = tid & 63;
        const float4* h4 = (const float4*)h2;
        float4 hr0 = h4[l], hr1 = h4[64 + l], hr2 = h4[128 + l], hr3 = h4[192 + l];
        for (int o = w; o < 51; o += 16) {
            int rm = (o < 48) ? o : (48 + o);
            int rv = (o < 48) ? (o + 48) : (51 + o);
            const float* wpm = WT + rm * 1024 + l * 4;
            const float* wpv = WT + rv * 1024 + l * 4;
            float4 wm0 = *(const float4*)(wpm);
            float4 wm1 = *(const float4*)(wpm + 256);
            float4 wm2 = *(const float4*)(wpm + 512);
            float4 wm3 = *(const float4*)(wpm + 768);
            float4 wv0 = *(const float4*)(wpv);
            float4 wv1 = *(const float4*)(wpv + 256);
            float4 wv2 = *(const float4*)(wpv + 512);
            float4 wv3 = *(const float4*)(wpv + 768);
            float am = 0.f, av = 0.f;
            am = fmaf(hr0.x, wm0.x, am); am = fmaf(hr0.y, wm0.y, am);
            am = fmaf(hr0.z, wm0.z, am); am = fmaf(hr0.w, wm0.w, am);
            av = fmaf(hr0.x, wv0.x, av); av = fmaf(hr0.y, wv0.y, av);
            av = fmaf(hr0.z, wv0.z, av); av = fmaf(hr0.w, wv0.w, av);
            am = fmaf(hr1.x, wm1.x, am); am = fmaf(hr1.y, wm1.y, am);
            am = fmaf(hr1.z, wm1.z, am); am = fmaf(hr1.w, wm1.w, am);
            av = fmaf(hr1.x, wv1.x, av); av = fmaf(hr1.y, wv1.y, av);
            av = fmaf(hr1.z, wv1.z, av); av = fmaf(hr1.w, wv1.w, av);
            am = fmaf(hr2.x, wm2.x, am); am = fmaf(hr2.y, wm2.y, am);
            am = fmaf(hr2.z, wm2.z, am); am = fmaf(hr2.w, wm2.w, am);
            av = fmaf(hr2.x, wv2.x, av); av = fmaf(hr2.y, wv2.y, av);
            av = fmaf(hr2.z, wv2.z, av); av = fmaf(hr2.w, wv2.w, av);
            am = fmaf(hr3.x, wm3.x, am); am = fmaf(hr3.y, wm3.y, am);
            am = fmaf(hr3.z, wm3.z, am); am = fmaf(hr3.w, wm3.w, am);
            av = fmaf(hr3.x, wv3.x, av); av = fmaf(hr3.y, wv3.y, av);
            av = fmaf(hr3.z, wv3.z, av); av = fmaf(hr3.w, wv3.w, av);
#pragma unroll
            for (int s = 32; s; s >>= 1) {
                am += __shfl_xor(am, s, 64);
                av += __shfl_xor(av, s, 64);
            }
            if (l == 0) {
                if (o < 48) {
                    float umu = tanhf(am + bum[o]);
                    float uvar = expf(fmaxf(av + buv[o], -6.f));   // threshold(-6,-6)
                    u_raw[o] = umu + uvar * eps_u[b * 48 + o];
                } else {
                    int n = o - 48;
                    float gmu = tanhf(am + bgm[n]);
                    float gpre = av + bgv[n];
                    float gvar = expf(gpre > -6.f ? gpre : 6.f);   // threshold(-6,6)
                    u_raw[o] = gmu + gvar * eps_g[b * 3 + n];
                }
            }
        }
    }
    __syncthreads();

    // ---- compositing setup ----
    if (tid < 16) {
        float ang = u_raw[tid * 3 + 0];
        float tx = u_raw[tid * 3 + 1], ty = u_raw[tid * 3 + 2];
        pc[tid] = cosf(ang);
        psn[tid] = sinf(ang);
        ptx[tid] = tx;
        pty[tid] = ty;
        float ax = fminf(fmaxf(32.f * tx, -16384.f), 16384.f);
        float fax = floorf(ax);
        pwx[tid] = ax - fax;
        pix[tid] = (int)fax;
        float ay = fminf(fmaxf(32.f * ty, -16384.f), 16384.f);
        float fay = floorf(ay);
        pwy[tid] = ay - fay;
        piy[tid] = (int)fay;
    }
    __syncthreads();

    int j = tid & 63;
    int i0 = (tid >> 6) * 4;
    float xnv = (float)(2 * j + 1) * (1.f / 64.f) - 1.f;
    float ynv0 = (float)(2 * i0 + 1) * (1.f / 64.f) - 1.f;

    float num[4] = {}, den[4] = {};

    // ---- p-loop: software-pipelined (load part p+1 while consuming p) ----
    auto load_taps = [&](int p) -> PTaps {
        PTaps T;
        int dx = 8 * (p & 3) - 12;
        int dy = 8 * (p >> 2) - 12;
        T.c = pc[p]; T.s = psn[p]; T.tx = ptx[p]; T.ty = pty[p];
        float wx = pwx[p]; T.wy = pwy[p];
        int ix = pix[p]; T.iy = piy[p];
        int iY = T.iy + dy;
        int x0 = j + ix;
        int X = x0 + dx;
        bool vc0 = ((unsigned)x0 < 64u) && ((unsigned)X < 64u);
        bool vc1 = ((unsigned)(x0 + 1) < 64u) && ((unsigned)(X + 1) < 64u);
        T.w0 = vc0 ? (1.f - wx) : 0.f;
        T.w1 = vc1 ? wx : 0.f;
        int Xc0 = min(max(X, 0), 63);
        int Xc1 = min(max(X + 1, 0), 63);
        const float* pl = Mb + ((size_t)p << 12);
#pragma unroll
        for (int r = 0; r < 5; r++) {
            int ri = i0 + r + iY;
            int ric = min(max(ri, 0), 63);
            const float* row = pl + (ric << 6);
            T.t[2 * r]     = row[Xc0];
            T.t[2 * r + 1] = row[Xc1];
        }
        return T;
    };

    auto consume = [&](int p, const PTaps& T) {
        int dx = 8 * (p & 3) - 12;
        int dy = 8 * (p >> 2) - 12;
        int iY = T.iy + dy;
        float R[5];
#pragma unroll
        for (int r = 0; r < 5; r++) {
            int i = i0 + r;
            int ri = i + iY;
            bool vr = ((unsigned)(i + T.iy) < 64u) && ((unsigned)ri < 64u);
            float val = fmaf(T.w0, T.t[2 * r], T.w1 * T.t[2 * r + 1]);
            R[r] = vr ? val : 0.f;
        }
        float gx0 = fmaf(-T.s, ynv0, fmaf(T.c, xnv, T.tx));
        float gy0 = fmaf(T.c, ynv0, fmaf(T.s, xnv, T.ty));
        float xs = fmaf(gx0, 32.f, 31.5f);
        float ysv = fmaf(gy0, 32.f, 31.5f);
        int ox = 24 - dx, oy = 24 - dy;
        float oxf = (float)ox, oyf = (float)oy;
        const float* pp = patch + (p << 8);
#pragma unroll
        for (int r = 0; r < 4; r++) {
            float km = fmaf(T.wy, R[r + 1] - R[r], R[r]);
            den[r] += km;
            if (xs >= oxf - 1.f && xs < oxf + 16.f &&
                ysv >= oyf - 1.f && ysv < oyf + 16.f) {
                float xf = floorf(xs), yf = floorf(ysv);
                float wxx = xs - xf, wyy = ysv - yf;
                int a0 = (int)yf - oy;
                int b0c = (int)xf - ox;
                float v00 = 0.f, v10 = 0.f, v01 = 0.f, v11 = 0.f;
                if ((unsigned)a0 < 16u) {
                    const float* pr = pp + a0 * 16;
                    if ((unsigned)b0c < 16u) v00 = pr[b0c];
                    if ((unsigned)(b0c + 1) < 16u) v10 = pr[b0c + 1];
                }
                if ((unsigned)(a0 + 1) < 16u) {
                    const float* pr = pp + (a0 + 1) * 16;
                    if ((unsigned)b0c < 16u) v01 = pr[b0c];
                    if ((unsigned)(b0c + 1) < 16u) v11 = pr[b0c + 1];
                }
                float top = fmaf(wxx, v10 - v00, v00);
                float bot = fmaf(wxx, v11 - v01, v01);
                float xp = fmaf(wyy, bot - top, top);
                num[r] = fmaf(xp, km, num[r]);
            }
            xs -= T.s;   // d(xs)/d(row) = -s
            ysv += T.c;  // d(ys)/d(row) = +c
        }
    };

    PTaps Ta = load_taps(0);
#pragma unroll
    for (int p = 0; p < 16; p += 2) {
        PTaps Tb = load_taps(p + 1);
        consume(p, Ta);
        if (p + 2 < 16) Ta = load_taps(p + 2);
        consume(p + 1, Tb);
    }

#pragma unroll
    for (int r = 0; r < 4; r++) {
        float d = (den[r] == 0.f) ? 1.f : den[r];
        xl[(i0 + r) * 64 + j] = num[r] / d;
    }
    __syncthreads();

    // ---- global gu transform (fused) ----
    float ang = u_raw[48], gtx = u_raw[49], gty = u_raw[50];
    float cg = cosf(ang), sg = sinf(ang);
    float* ob = out + ((size_t)b << 12);
#pragma unroll
    for (int r = 0; r < 4; r++) {
        int i = i0 + r;
        float ynv = (float)(2 * i + 1) * (1.f / 64.f) - 1.f;
        float gx = cg * xnv - sg * ynv + gtx;
        float gy = sg * xnv + cg * ynv + gty;
        gx = fminf(fmaxf(gx, -8.f), 8.f);
        gy = fminf(fmaxf(gy, -8.f), 8.f);
        float xs = fmaf(gx, 32.f, 31.5f);
        float ysv = fmaf(gy, 32.f, 31.5f);
        float xf = floorf(xs), yf = floorf(ysv);
        float wx = xs - xf, wy = ysv - yf;
        int x0 = (int)xf, y0 = (int)yf;
        float v00 = 0.f, v10 = 0.f, v01 = 0.f, v11 = 0.f;
        bool vx0 = (unsigned)x0 < 64u, vx1 = (unsigned)(x0 + 1) < 64u;
        if ((unsigned)y0 < 64u) {
            const float* row = xl + y0 * 64;
            if (vx0) v00 = row[x0];
            if (vx1) v10 = row[x0 + 1];
        }
        if ((unsigned)(y0 + 1) < 64u) {
            const float* row = xl + (y0 + 1) * 64;
            if (vx0) v01 = row[x0];
            if (vx1) v11 = row[x0 + 1];
        }
        float top = fmaf(wx, v10 - v00, v00);
        float bot = fmaf(wx, v11 - v01, v01);
        ob[i * 64 + j] = fmaf(wy, bot - top, top);
    }
}

// ---------------------------------------------------------------------------
extern "C" void kernel_launch(void* const* d_in, const int* in_sizes, int n_in,
                              void* d_out, int out_size, void* d_ws, size_t ws_size,
                              hipStream_t stream)
{
    (void)in_sizes; (void)n_in; (void)out_size; (void)ws_size;
    const float* inputs = (const float*)d_in[0];
    const float* W1  = (const float*)d_in[1];
    const float* b1  = (const float*)d_in[2];
    const float* W2  = (const float*)d_in[3];
    const float* b2  = (const float*)d_in[4];
    const float* Wum = (const float*)d_in[5];
    const float* bum = (const float*)d_in[6];
    const float* Wuv = (const float*)d_in[7];
    const float* buv = (const float*)d_in[8];
    const float* Wgm = (const float*)d_in[9];
    const float* bgm = (const float*)d_in[10];
    const float* Wgv = (const float*)d_in[11];
    const float* bgv = (const float*)d_in[12];
    const float* Wz  = (const float*)d_in[13];
    const float* Mm  = (const float*)d_in[14];
    const float* eps_u = (const float*)d_in[15];
    const float* eps_g = (const float*)d_in[16];

    float* ws = (float*)d_ws;
    float* psum      = ws;                     // 8 x 262144 floats
    float* parts_buf = psum + 8 * PSUM_STRIDE; // 4,096
    float* WTh_buf   = parts_buf + 4096;       // 104,448
    unsigned short* us = (unsigned short*)(WTh_buf + 104448);
    unsigned short* Ahi   = us;                 // 1,048,576
    unsigned short* Alo   = Ahi + 1048576;
    unsigned short* W1Thi = Alo + 1048576;      // 4,194,304
    unsigned short* W1Tlo = W1Thi + 4194304;
    unsigned short* W2Thi = W1Tlo + 4194304;    // 1,048,576
    unsigned short* W2Tlo = W2Thi + 1048576;
    unsigned short* H1hi  = W2Tlo + 1048576;    // 262,144
    unsigned short* H1lo  = H1hi + 262144;

    // Preprocessing (single fused kernel -- r3-proven faster than the split)
    prep_all<<<6568, 256, 0, stream>>>(inputs, W1, W2, Wum, Wuv, Wgm, Wgv, Wz,
                                       Ahi, Alo, W1Thi, W1Tlo, W2Thi, W2Tlo,
                                       WTh_buf, parts_buf);

    // MLP layer 1: [256,4096] @ [4096,1024], bf16x3 MFMA split-K=8
    gemm_bf16x3<<<dim3(16, 4, SPLITK), 256, 0, stream>>>(Ahi, Alo, W1Thi, W1Tlo,
                                                         psum, 4096, 4096 / SPLITK);
    reduce_bias_relu_split<<<256, 256, 0, stream>>>(psum, b1, H1hi, H1lo);
    // MLP layer 2: [256,1024] @ [1024,1024], split-K=8
    gemm_bf16x3<<<dim3(16, 4, SPLITK), 256, 0, stream>>>(H1hi, H1lo, W2Thi, W2Tlo,
                                                         psum, 1024, 1024 / SPLITK);
    // Heads + compositing + global transform -> out [256,1,64,64]
    composite_direct<<<256, 1024, 0, stream>>>(psum, b2, WTh_buf, bum, buv,
                                               bgm, bgv, eps_u, eps_g,
                                               Mm, parts_buf, (float*)d_out);
}